// Round 11
// baseline (315.218 us; speedup 1.0000x reference)
//
#include <hip/hip_runtime.h>
#include <hip/hip_bf16.h>

#define N_NODES 50000
#define N_EDGES 800000
#define N_GRAPHS 64
#define HEADS 4
#define IN_CH 128
#define HID 64
#define F1 256  // HEADS*HID
#define OUT_CH 32
#define F2 128  // HEADS*OUT_CH
#define POOL_SPLITS 16
#define SCAN_B 256
#define SCAN_NB ((N_NODES + SCAN_B - 1) / SCAN_B)  // 196
#define GEMM_GRID ((N_NODES + 63) / 64)            // 782 (64 rows/block, 1 tile/wave)
#define COUNT_GRID ((N_EDGES + 255) / 256)         // 3125

typedef unsigned short ushortT;
typedef unsigned int uintT;
typedef short v8s __attribute__((ext_vector_type(8)));
typedef float v4f __attribute__((ext_vector_type(4)));
typedef float v2f __attribute__((ext_vector_type(2)));

__device__ __forceinline__ ushortT f2bf(float f) {
    union { float f; unsigned int i; } v; v.f = f;
    unsigned int x = v.i;
    unsigned int r = (x + 0x7fffu + ((x >> 16) & 1u)) >> 16;  // RNE
    return (ushortT)r;
}
__device__ __forceinline__ float bf_lo(uintT w) {
    union { unsigned int i; float f; } v; v.i = w << 16; return v.f;
}
// fp8 e4m3 (OCP on gfx950) via HW converts
__device__ __forceinline__ unsigned char f2fp8(float f) {
    return (unsigned char)__builtin_amdgcn_cvt_pk_fp8_f32(f, f, 0u, false);
}

// ---- one-time weight pack into bf16 B-fragment image + fused zeroing of
// i_cnt and the sync counters (no memset launches; single stream =>
// launches serialize, fewer is faster) ----
__device__ __forceinline__ void packW_one(const float* __restrict__ W,
                                          uint4* __restrict__ dst,
                                          int i, int FIN, int FOUT) {
    int KC = FIN / 32;
    int lane = i & 63, g = i >> 6;
    int kc = g % KC, nt = g / KC;
    int n = nt * 16 + (lane & 15);
    int kbase = kc * 32 + (lane >> 4) * 8;
    union { uint4 q; ushortT u[8]; } pk;
#pragma unroll
    for (int j = 0; j < 8; j++) pk.u[j] = f2bf(W[(kbase + j) * FOUT + n]);
    dst[i] = pk.q;
}

__global__ __launch_bounds__(256) void k_packw(
        const float* __restrict__ W1, const float* __restrict__ W2,
        uint4* __restrict__ wpk, int* __restrict__ counts,
        int* __restrict__ sync) {
    int i = blockIdx.x * 256 + threadIdx.x;  // 8192 = 4096 (W1) + 4096 (W2)
    if (i < 4096) packW_one(W1, wpk, i, IN_CH, F1);
    else          packW_one(W2, wpk + 4096, i - 4096, F1, F2);
    for (int j = i; j < N_NODES; j += 8192) counts[j] = 0;  // fused memset
    if (i < 128) sync[i] = 0;  // done-counters for fused scan / poolhead
}

// ---- MFMA GEMM, 64-row block, ONE 16-row tile per wave (r10 measured
// best shape). W image stays L2-resident, no LDS. ----
template <int FIN, int FOUT, bool ABF16>
__device__ __forceinline__ void gemm_body(const void* __restrict__ A,
                                          const uint4* __restrict__ Wpk,
                                          const float* __restrict__ ASrc,
                                          const float* __restrict__ ADst,
                                          unsigned char* __restrict__ out,
                                          float* __restrict__ s_out_g,
                                          float* __restrict__ d_out_g,
                                          int nrows, int bid) {
    constexpr int KC = FIN / 32;
    constexpr int NT = FOUT / 16;
    constexpr int NTH = (FOUT / HEADS) / 16;  // nt tiles per head
    int tid = threadIdx.x;
    int wave = tid >> 6, lane = tid & 63;
    long row0 = (long)bid * 64 + wave * 16;
    if (row0 >= nrows) return;  // wave-uniform (nrows % 16 == 0)
    int m = lane & 15, b = lane >> 4;

    v8s af[KC];
    if (ABF16) {
        const ushortT* Ab = (const ushortT*)A;
#pragma unroll
        for (int kc = 0; kc < KC; kc++) {
            union { v8s v; uint4 q; } u;
            u.q = *(const uint4*)(Ab + (row0 + m) * FIN + kc * 32 + b * 8);
            af[kc] = u.v;
        }
    } else {
        const float* Af = (const float*)A;
#pragma unroll
        for (int kc = 0; kc < KC; kc++) {
            union { v8s v; ushortT u[8]; } u;
            const float* p = Af + (row0 + m) * FIN + kc * 32 + b * 8;
#pragma unroll
            for (int j = 0; j < 8; j++) u.u[j] = f2bf(p[j]);
            af[kc] = u.v;
        }
    }

    float sp[4] = {0,0,0,0}, dp[4] = {0,0,0,0};
    float sk[4], dk[4];
#pragma unroll
    for (int nt = 0; nt < NT; nt++) {
        v4f c = {0.f, 0.f, 0.f, 0.f};
#pragma unroll
        for (int kc = 0; kc < KC; kc++) {
            union { v8s v; uint4 q; } bu;
            bu.q = Wpk[(nt * KC + kc) * 64 + lane];
            c = __builtin_amdgcn_mfma_f32_16x16x32_bf16(af[kc], bu.v, c, 0, 0, 0);
        }
        // C/D: col = lane&15, row = (lane>>4)*4 + reg   [measured m89/m91]
        int col = nt * 16 + m;
        float av = ASrc[col], dv = ADst[col];
        long r0 = row0 + b * 4;
#pragma unroll
        for (int reg = 0; reg < 4; reg++) {
            out[(r0 + reg) * FOUT + col] = f2fp8(c[reg]);
            sp[reg] += c[reg] * av;
            dp[reg] += c[reg] * dv;
        }
        if ((nt % NTH) == NTH - 1) {  // head boundary: reduce over 16 m-lanes
#pragma unroll
            for (int o = 1; o < 16; o <<= 1) {
#pragma unroll
                for (int reg = 0; reg < 4; reg++) {
                    sp[reg] += __shfl_xor(sp[reg], o, 64);
                    dp[reg] += __shfl_xor(dp[reg], o, 64);
                }
            }
            int hd = nt / NTH;
#pragma unroll
            for (int reg = 0; reg < 4; reg++) {
                if (m == hd) { sk[reg] = sp[reg]; dk[reg] = dp[reg]; }
                sp[reg] = 0.f; dp[reg] = 0.f;
            }
        }
    }
    if (m < HEADS) {
        long r0 = row0 + b * 4;
#pragma unroll
        for (int reg = 0; reg < 4; reg++) {
            s_out_g[(r0 + reg) * HEADS + m] = sk[reg];
            d_out_g[(r0 + reg) * HEADS + m] = dk[reg];
        }
    }
}

// ---- mega kernel: gemm1 FIRST (782 blocks) + edge count behind (3125
// cheap atomic blocks). Intra-kernel fusion = the only concurrency on a
// single stream. Count records rank so the later scatter is atomic-free. ----
__global__ __launch_bounds__(256) void k_mega1(
        const float* __restrict__ x, const uint4* __restrict__ wpk,
        const float* __restrict__ asrc1, const float* __restrict__ adst1,
        unsigned char* __restrict__ u_h, float* __restrict__ f_s,
        float* __restrict__ f_d, const int* __restrict__ ei,
        int* __restrict__ counts, int* __restrict__ rank) {
    if (blockIdx.x < GEMM_GRID) {
        gemm_body<IN_CH, F1, false>(x, wpk, asrc1, adst1, u_h, f_s, f_d,
                                    N_NODES, blockIdx.x);
    } else {
        int e = (blockIdx.x - GEMM_GRID) * 256 + threadIdx.x;
        if (e < N_EDGES) {
            int dst = ei[N_EDGES + e];
            rank[e] = atomicAdd(&counts[dst], 1);
        }
    }
}

__global__ __launch_bounds__(256) void k_gemm2(
        const ushortT* __restrict__ A, const uint4* __restrict__ wpk2,
        const float* __restrict__ asrc2, const float* __restrict__ adst2,
        unsigned char* __restrict__ u_h, float* __restrict__ f_s,
        float* __restrict__ f_d) {
    gemm_body<F1, F2, true>(A, wpk2, asrc2, adst2, u_h, f_s, f_d,
                            N_NODES, blockIdx.x);
}

// ---- FUSED scan: block-local exclusive scan; the LAST block to finish
// (device-scope acq_rel counter) performs the cross-block scan, grand
// total, and graph-bounds search. Replaces the scan1+scan2 launches.
// Cross-XCD safety: writers fence before the counter bump; the winner
// reads bsum via agent-scope relaxed atomic loads (bypasses stale L2). ----
__global__ void k_scan(const int* __restrict__ counts, int* __restrict__ offs,
                       int* __restrict__ bsum, int* __restrict__ bbase,
                       const int* __restrict__ batch, int* __restrict__ bounds,
                       int* __restrict__ done) {
    __shared__ int sh[SCAN_B];
    __shared__ int amLast;
    int b = blockIdx.x, t = threadIdx.x;
    int i = b * SCAN_B + t;
    int v = (i < N_NODES) ? counts[i] : 0;
    sh[t] = v;
    __syncthreads();
    for (int o = 1; o < SCAN_B; o <<= 1) {
        int add = (t >= o) ? sh[t - o] : 0;
        __syncthreads();
        sh[t] += add;
        __syncthreads();
    }
    if (i < N_NODES) offs[i] = sh[t] - v;  // block-local exclusive
    if (t == SCAN_B - 1) bsum[b] = sh[t];
    __threadfence();   // each thread flushes its own stores to device scope
    __syncthreads();
    if (t == 0) {
        int old = __hip_atomic_fetch_add(done, 1, __ATOMIC_ACQ_REL,
                                         __HIP_MEMORY_SCOPE_AGENT);
        amLast = (old == SCAN_NB - 1);
    }
    __syncthreads();
    if (!amLast) return;
    // ---- winner block: cross-block scan (old k_scan2) ----
    int v2 = (t < SCAN_NB)
                 ? __hip_atomic_load(&bsum[t], __ATOMIC_RELAXED,
                                     __HIP_MEMORY_SCOPE_AGENT)
                 : 0;
    sh[t] = v2;
    __syncthreads();
    for (int o = 1; o < SCAN_B; o <<= 1) {
        int add = (t >= o) ? sh[t - o] : 0;
        __syncthreads();
        sh[t] += add;
        __syncthreads();
    }
    if (t < SCAN_NB) bbase[t] = sh[t] - v2;     // exclusive base per block
    if (t == SCAN_B - 1) offs[N_NODES] = sh[t]; // grand total (= N_EDGES)
    // graph boundaries via binary search on sorted batch
    if (t <= N_GRAPHS) {
        int lo = 0, hi = N_NODES;
        while (lo < hi) {
            int mid = (lo + hi) >> 1;
            if (batch[mid] < t) lo = mid + 1; else hi = mid;
        }
        bounds[t] = lo;
    }
}

// ---- scatter: ATOMIC-FREE (rank precomputed during count) ----
__global__ void k_scatter(const int* __restrict__ ei, const int* __restrict__ offs,
                          const int* __restrict__ bbase, const int* __restrict__ rank,
                          int* __restrict__ csr_src) {
    int e = blockIdx.x * blockDim.x + threadIdx.x;
    if (e >= N_EDGES) return;
    int src = ei[e], dst = ei[N_EDGES + e];
    int pos = offs[dst] + bbase[dst >> 8] + rank[e];
    csr_src[pos] = src;
}

// ---- fused segment-softmax + aggregation: TWO nodes per wave (32 lanes
// each), no barriers. (r3/r10 measured-best shape.) ----
template <int C, int VEC, int WPB, int CHUNK>
__global__ __launch_bounds__(64 * WPB) void k_agg(
        const unsigned char* __restrict__ hb, const float* __restrict__ s,
        const float* __restrict__ d, const int* __restrict__ offs,
        const int* __restrict__ bbase, const int* __restrict__ csr_src,
        const float* __restrict__ bias, ushortT* __restrict__ xout) {
    constexpr int F = HEADS * C;
    constexpr int TPN = F / VEC;  // lanes per node
    static_assert(TPN == 32, "two nodes per wave");
    static_assert(C / VEC == 8, "head = tl>>3");
    static_assert(N_NODES % (WPB * 2) == 0, "exact grid");
    __shared__ int lsrc[WPB][2][CHUNK];
    __shared__ float lex[WPB][2][CHUNK * HEADS];
    int wv = threadIdx.x >> 6;
    int t = threadIdx.x & 63;
    int half = t >> 5, tl = t & 31;
    int n = (blockIdx.x * WPB + wv) * 2 + half;
    int h = tl >> 3;
    int beg = offs[n] + bbase[n >> 8];
    int np1 = n + 1;
    int end = (np1 < N_NODES) ? offs[np1] + bbase[np1 >> 8] : offs[N_NODES];
    float4 dn = *(const float4*)(d + n * 4);

    // implicit self-loop: init sumex/acc from own s,d,h (outside the hot loop)
    float4 svn = *(const float4*)(s + n * 4);
    float ssel = (h == 0) ? svn.x : (h == 1) ? svn.y : (h == 2) ? svn.z : svn.w;
    float dsel = (h == 0) ? dn.x : (h == 1) ? dn.y : (h == 2) ? dn.z : dn.w;
    float es = ssel + dsel; es = es > 0.f ? es : 0.2f * es;
    float exs = __expf(es);
    float sumex = exs;
    float acc[VEC];
    if (VEC == 8) {
        uint2 w = ((const uint2*)hb)[(long)n * TPN + tl];
        v2f p0 = __builtin_amdgcn_cvt_pk_f32_fp8(w.x, false);
        v2f p1 = __builtin_amdgcn_cvt_pk_f32_fp8(w.x, true);
        v2f p2 = __builtin_amdgcn_cvt_pk_f32_fp8(w.y, false);
        v2f p3 = __builtin_amdgcn_cvt_pk_f32_fp8(w.y, true);
        acc[0] = exs * p0.x; acc[1] = exs * p0.y;
        acc[2] = exs * p1.x; acc[3] = exs * p1.y;
        acc[4] = exs * p2.x; acc[5] = exs * p2.y;
        acc[6] = exs * p3.x; acc[7] = exs * p3.y;
    } else {
        uintT w = ((const uintT*)hb)[(long)n * TPN + tl];
        v2f p0 = __builtin_amdgcn_cvt_pk_f32_fp8(w, false);
        v2f p1 = __builtin_amdgcn_cvt_pk_f32_fp8(w, true);
        acc[0] = exs * p0.x; acc[1] = exs * p0.y;
        acc[2] = exs * p1.x; acc[3] = exs * p1.y;
    }

    int tot = end - beg;                      // uniform within a half
    int totO = __shfl_xor(tot, 32, 64);       // other half's count
    int maxTot = max(tot, totO);
    for (int base = 0; base < maxTot; base += CHUNK) {
        int cnt = min(CHUNK, tot - base); if (cnt < 0) cnt = 0;
        int cntW = min(CHUNK, maxTot - base);  // wave-uniform loop bound
        // phase 1: each half stages its own node's edges (32 lanes active)
        for (int i = tl; i < cnt; i += TPN) {
            int sn = csr_src[beg + base + i];
            lsrc[wv][half][i] = sn;
            float4 sv = *(const float4*)(s + sn * 4);
            float e0 = sv.x + dn.x; e0 = e0 > 0.f ? e0 : 0.2f * e0;
            float e1 = sv.y + dn.y; e1 = e1 > 0.f ? e1 : 0.2f * e1;
            float e2 = sv.z + dn.z; e2 = e2 > 0.f ? e2 : 0.2f * e2;
            float e3 = sv.w + dn.w; e3 = e3 > 0.f ? e3 : 0.2f * e3;
            float4 exv = { __expf(e0), __expf(e1), __expf(e2), __expf(e3) };
            *(float4*)&lex[wv][half][i * 4] = exv;
        }
        // intra-wave LDS write->read ordering (no block barrier needed)
        asm volatile("s_waitcnt lgkmcnt(0)" ::: "memory");
        // phase 2: both halves accumulate in lockstep; shorter half padded
        // with ex=0 / sn=0 (branchless, finite data -> adds exact 0)
#pragma unroll 4
        for (int i = 0; i < cntW; i++) {
            bool act = i < cnt;
            float ex = act ? lex[wv][half][i * 4 + h] : 0.f;
            int sn = act ? lsrc[wv][half][i] : 0;
            sumex += ex;
            if (VEC == 8) {
                uint2 w = ((const uint2*)hb)[(long)sn * TPN + tl];
                v2f p0 = __builtin_amdgcn_cvt_pk_f32_fp8(w.x, false);
                v2f p1 = __builtin_amdgcn_cvt_pk_f32_fp8(w.x, true);
                v2f p2 = __builtin_amdgcn_cvt_pk_f32_fp8(w.y, false);
                v2f p3 = __builtin_amdgcn_cvt_pk_f32_fp8(w.y, true);
                acc[0] += ex * p0.x; acc[1] += ex * p0.y;
                acc[2] += ex * p1.x; acc[3] += ex * p1.y;
                acc[4] += ex * p2.x; acc[5] += ex * p2.y;
                acc[6] += ex * p3.x; acc[7] += ex * p3.y;
            } else {
                uintT w = ((const uintT*)hb)[(long)sn * TPN + tl];
                v2f p0 = __builtin_amdgcn_cvt_pk_f32_fp8(w, false);
                v2f p1 = __builtin_amdgcn_cvt_pk_f32_fp8(w, true);
                acc[0] += ex * p0.x; acc[1] += ex * p0.y;
                acc[2] += ex * p1.x; acc[3] += ex * p1.y;
            }
        }
        asm volatile("" ::: "memory");
    }
    float inv = 1.f / (sumex + 1e-16f);
    float o[VEC];
#pragma unroll
    for (int j = 0; j < VEC; j++)
        o[j] = fmaxf(acc[j] * inv + bias[tl * VEC + j], 0.f);
    if (VEC == 8) {
        uint4 pk;
        pk.x = (uintT)f2bf(o[0]) | ((uintT)f2bf(o[1]) << 16);
        pk.y = (uintT)f2bf(o[2]) | ((uintT)f2bf(o[3]) << 16);
        pk.z = (uintT)f2bf(o[4]) | ((uintT)f2bf(o[5]) << 16);
        pk.w = (uintT)f2bf(o[6]) | ((uintT)f2bf(o[7]) << 16);
        ((uint4*)xout)[(long)n * TPN + tl] = pk;
    } else {
        uint2 pk;
        pk.x = (uintT)f2bf(o[0]) | ((uintT)f2bf(o[1]) << 16);
        pk.y = (uintT)f2bf(o[2]) | ((uintT)f2bf(o[3]) << 16);
        ((uint2*)xout)[(long)n * TPN + tl] = pk;
    }
}

// ---- FUSED pool+head: block (g,s) sums its slice and writes a partial;
// the LAST split-block of each graph (per-graph acq_rel counter) reduces
// the 16 partials (agent-scope loads), means, applies Wout, softmaxes.
// Replaces the pool+head launches. ----
__global__ void k_poolhead(const ushortT* __restrict__ x2,
                           const int* __restrict__ bounds,
                           float* __restrict__ partial, int* __restrict__ gdone,
                           const float* __restrict__ Wout,
                           const float* __restrict__ bout,
                           float* __restrict__ out) {
    __shared__ int amLast;
    __shared__ float red0[F2], red1[F2];
    int g = blockIdx.x, s = blockIdx.y;
    int t = threadIdx.x;  // F2 threads
    int n0 = bounds[g], n1 = bounds[g + 1];
    int len = n1 - n0;
    int a = n0 + (int)((long)len * s / POOL_SPLITS);
    int b = n0 + (int)((long)len * (s + 1) / POOL_SPLITS);
    float acc = 0.f;
    for (int n = a; n < b; n++) acc += bf_lo((uintT)x2[(long)n * F2 + t]);
    partial[((long)g * POOL_SPLITS + s) * F2 + t] = acc;
    __threadfence();   // flush own partial to device scope
    __syncthreads();
    if (t == 0) {
        int old = __hip_atomic_fetch_add(&gdone[g], 1, __ATOMIC_ACQ_REL,
                                         __HIP_MEMORY_SCOPE_AGENT);
        amLast = (old == POOL_SPLITS - 1);
    }
    __syncthreads();
    if (!amLast) return;
    // ---- winner block: head for graph g ----
    float cnt = fmaxf((float)len, 1.0f);
    float sum = 0.f;
    for (int ss = 0; ss < POOL_SPLITS; ss++)
        sum += __hip_atomic_load(&partial[((long)g * POOL_SPLITS + ss) * F2 + t],
                                 __ATOMIC_RELAXED, __HIP_MEMORY_SCOPE_AGENT);
    float p = sum / cnt;
    red0[t] = p * Wout[t * 2 + 0];
    red1[t] = p * Wout[t * 2 + 1];
    __syncthreads();
    for (int off = F2 / 2; off > 0; off >>= 1) {
        if (t < off) { red0[t] += red0[t + off]; red1[t] += red1[t + off]; }
        __syncthreads();
    }
    if (t == 0) {
        float l0 = red0[0] + bout[0];
        float l1 = red1[0] + bout[1];
        float m = fmaxf(l0, l1);
        float e0 = __expf(l0 - m), e1 = __expf(l1 - m);
        float inv = 1.f / (e0 + e1);
        out[g * 2 + 0] = e0 * inv;
        out[g * 2 + 1] = e1 * inv;
    }
}

extern "C" void kernel_launch(void* const* d_in, const int* in_sizes, int n_in,
                              void* d_out, int out_size, void* d_ws, size_t ws_size,
                              hipStream_t stream) {
    const float* x     = (const float*)d_in[0];
    const int*   ei    = (const int*)d_in[1];
    const int*   batch = (const int*)d_in[2];
    const float* W1    = (const float*)d_in[3];
    const float* asrc1 = (const float*)d_in[4];
    const float* adst1 = (const float*)d_in[5];
    const float* b1    = (const float*)d_in[6];
    const float* W2    = (const float*)d_in[7];
    const float* asrc2 = (const float*)d_in[8];
    const float* adst2 = (const float*)d_in[9];
    const float* b2    = (const float*)d_in[10];
    const float* Wout  = (const float*)d_in[11];
    const float* bout  = (const float*)d_in[12];

    char* ws = (char*)d_ws;
    size_t off = 0;
    auto alloc = [&](size_t bytes) -> void* {
        void* p = ws + off;
        off += (bytes + 255) / 256 * 256;
        return p;
    };
    unsigned char* u_h = (unsigned char*)alloc((size_t)N_NODES * F1);  // fp8 h (both layers)
    ushortT* u_x1  = (ushortT*)alloc(sizeof(ushortT) * (size_t)N_NODES * F1);
    ushortT* u_x2  = (ushortT*)alloc(sizeof(ushortT) * (size_t)N_NODES * F2);
    uint4*   wpk   = (uint4*)alloc(sizeof(uint4) * 8192);  // W1|W2 fragment images
    float*   f_s   = (float*)alloc(sizeof(float) * (size_t)N_NODES * HEADS);
    float*   f_d   = (float*)alloc(sizeof(float) * (size_t)N_NODES * HEADS);
    int*     i_cnt = (int*)alloc(sizeof(int) * (size_t)N_NODES);
    int*     i_off = (int*)alloc(sizeof(int) * (size_t)(N_NODES + 1));
    int*     i_rnk = (int*)alloc(sizeof(int) * (size_t)N_EDGES);
    int*     i_csr = (int*)alloc(sizeof(int) * (size_t)N_EDGES);
    int*     i_bnd = (int*)alloc(sizeof(int) * (size_t)(N_GRAPHS + 1));
    int*     i_bs  = (int*)alloc(sizeof(int) * SCAN_NB);
    int*     i_bb  = (int*)alloc(sizeof(int) * SCAN_NB);
    int*     i_syn = (int*)alloc(sizeof(int) * 128);  // [0]=scan done, [1..64]=gdone
    float*   f_prt = (float*)alloc(sizeof(float) * (size_t)N_GRAPHS * POOL_SPLITS * F2);
    (void)ws_size; (void)in_sizes; (void)n_in; (void)out_size;

    // tiny W-only pack + fused zeroing of counts and sync counters
    k_packw<<<32, 256, 0, stream>>>(W1, W2, wpk, i_cnt, i_syn);

    // mega: gemm1 (782 blocks, 1 tile/wave) + CSR count-with-rank behind
    k_mega1<<<GEMM_GRID + COUNT_GRID, 256, 0, stream>>>(
        x, wpk, asrc1, adst1, u_h, f_s, f_d, ei, i_cnt, i_rnk);

    // fused scan (block scans + last-block cross-scan + bounds)
    k_scan<<<SCAN_NB, SCAN_B, 0, stream>>>(i_cnt, i_off, i_bs, i_bb, batch,
                                           i_bnd, &i_syn[0]);

    // atomic-free scatter using precomputed ranks
    k_scatter<<<COUNT_GRID, 256, 0, stream>>>(ei, i_off, i_bb, i_rnk, i_csr);

    int agg_grid = N_NODES / (4 * 2);  // 2 nodes/wave, 4 waves/block = 6250

    // Layer 1 aggregation (fp8 gather, 2 nodes per wave, VEC=8)
    k_agg<HID, 8, 4, 128><<<agg_grid, 256, 0, stream>>>(
        u_h, f_s, f_d, i_off, i_bb, i_csr, b1, u_x1);

    // Layer 2
    k_gemm2<<<GEMM_GRID, 256, 0, stream>>>(u_x1, wpk + 4096, asrc2, adst2,
                                           u_h, f_s, f_d);
    k_agg<OUT_CH, 4, 4, 128><<<agg_grid, 256, 0, stream>>>(
        u_h, f_s, f_d, i_off, i_bb, i_csr, b2, u_x2);

    // fused pool+head (per-graph last-block reduction)
    dim3 pgrid(N_GRAPHS, POOL_SPLITS);
    k_poolhead<<<pgrid, F2, 0, stream>>>(u_x2, i_bnd, f_prt, &i_syn[1],
                                         Wout, bout, (float*)d_out);
}

// Round 12
// 252.513 us; speedup vs baseline: 1.2483x; 1.2483x over previous
//
#include <hip/hip_runtime.h>
#include <hip/hip_bf16.h>

#define N_NODES 50000
#define N_EDGES 800000
#define N_GRAPHS 64
#define HEADS 4
#define IN_CH 128
#define HID 64
#define F1 256  // HEADS*HID
#define OUT_CH 32
#define F2 128  // HEADS*OUT_CH
#define POOL_SPLITS 16
#define SCAN_B 256
#define SCAN_NB ((N_NODES + SCAN_B - 1) / SCAN_B)  // 196
#define GEMM_GRID ((N_NODES + 63) / 64)            // 782 (64 rows/block, 1 tile/wave)
#define COUNT_GRID ((N_EDGES + 255) / 256)         // 3125

typedef unsigned short ushortT;
typedef unsigned int uintT;
typedef short v8s __attribute__((ext_vector_type(8)));
typedef float v4f __attribute__((ext_vector_type(4)));
typedef float v2f __attribute__((ext_vector_type(2)));

__device__ __forceinline__ ushortT f2bf(float f) {
    union { float f; unsigned int i; } v; v.f = f;
    unsigned int x = v.i;
    unsigned int r = (x + 0x7fffu + ((x >> 16) & 1u)) >> 16;  // RNE
    return (ushortT)r;
}
__device__ __forceinline__ float bf_lo(uintT w) {
    union { unsigned int i; float f; } v; v.i = w << 16; return v.f;
}
// fp8 e4m3 (OCP on gfx950) via HW converts
__device__ __forceinline__ unsigned char f2fp8(float f) {
    return (unsigned char)__builtin_amdgcn_cvt_pk_fp8_f32(f, f, 0u, false);
}
// accumulate 4 fp8 (one u32) scaled by ex into acc[0..3]
__device__ __forceinline__ void fp8x4_acc(uintT w, float ex, float* acc) {
    v2f p0 = __builtin_amdgcn_cvt_pk_f32_fp8(w, false);
    v2f p1 = __builtin_amdgcn_cvt_pk_f32_fp8(w, true);
    acc[0] += ex * p0.x; acc[1] += ex * p0.y;
    acc[2] += ex * p1.x; acc[3] += ex * p1.y;
}

// ---- one-time weight pack into bf16 B-fragment image + fused i_cnt zeroing
// (r11 lesson: do NOT fuse cross-block stages with device fences — a
// per-block __threadfence is an L2-writeback storm, ~50us. Launches are
// ~2us; keep separate kernels.) ----
__device__ __forceinline__ void packW_one(const float* __restrict__ W,
                                          uint4* __restrict__ dst,
                                          int i, int FIN, int FOUT) {
    int KC = FIN / 32;
    int lane = i & 63, g = i >> 6;
    int kc = g % KC, nt = g / KC;
    int n = nt * 16 + (lane & 15);
    int kbase = kc * 32 + (lane >> 4) * 8;
    union { uint4 q; ushortT u[8]; } pk;
#pragma unroll
    for (int j = 0; j < 8; j++) pk.u[j] = f2bf(W[(kbase + j) * FOUT + n]);
    dst[i] = pk.q;
}

__global__ __launch_bounds__(256) void k_packw(
        const float* __restrict__ W1, const float* __restrict__ W2,
        uint4* __restrict__ wpk, int* __restrict__ counts) {
    int i = blockIdx.x * 256 + threadIdx.x;  // 8192 = 4096 (W1) + 4096 (W2)
    if (i < 4096) packW_one(W1, wpk, i, IN_CH, F1);
    else          packW_one(W2, wpk + 4096, i - 4096, F1, F2);
    for (int j = i; j < N_NODES; j += 8192) counts[j] = 0;  // fused memset
}

// ---- MFMA GEMM, 64-row block, ONE 16-row tile per wave (r10 measured
// best shape). W image stays L2-resident, no LDS. ----
template <int FIN, int FOUT, bool ABF16>
__device__ __forceinline__ void gemm_body(const void* __restrict__ A,
                                          const uint4* __restrict__ Wpk,
                                          const float* __restrict__ ASrc,
                                          const float* __restrict__ ADst,
                                          unsigned char* __restrict__ out,
                                          float* __restrict__ s_out_g,
                                          float* __restrict__ d_out_g,
                                          int nrows, int bid) {
    constexpr int KC = FIN / 32;
    constexpr int NT = FOUT / 16;
    constexpr int NTH = (FOUT / HEADS) / 16;  // nt tiles per head
    int tid = threadIdx.x;
    int wave = tid >> 6, lane = tid & 63;
    long row0 = (long)bid * 64 + wave * 16;
    if (row0 >= nrows) return;  // wave-uniform (nrows % 16 == 0)
    int m = lane & 15, b = lane >> 4;

    v8s af[KC];
    if (ABF16) {
        const ushortT* Ab = (const ushortT*)A;
#pragma unroll
        for (int kc = 0; kc < KC; kc++) {
            union { v8s v; uint4 q; } u;
            u.q = *(const uint4*)(Ab + (row0 + m) * FIN + kc * 32 + b * 8);
            af[kc] = u.v;
        }
    } else {
        const float* Af = (const float*)A;
#pragma unroll
        for (int kc = 0; kc < KC; kc++) {
            union { v8s v; ushortT u[8]; } u;
            const float* p = Af + (row0 + m) * FIN + kc * 32 + b * 8;
#pragma unroll
            for (int j = 0; j < 8; j++) u.u[j] = f2bf(p[j]);
            af[kc] = u.v;
        }
    }

    float sp[4] = {0,0,0,0}, dp[4] = {0,0,0,0};
    float sk[4], dk[4];
#pragma unroll
    for (int nt = 0; nt < NT; nt++) {
        v4f c = {0.f, 0.f, 0.f, 0.f};
#pragma unroll
        for (int kc = 0; kc < KC; kc++) {
            union { v8s v; uint4 q; } bu;
            bu.q = Wpk[(nt * KC + kc) * 64 + lane];
            c = __builtin_amdgcn_mfma_f32_16x16x32_bf16(af[kc], bu.v, c, 0, 0, 0);
        }
        // C/D: col = lane&15, row = (lane>>4)*4 + reg   [measured m89/m91]
        int col = nt * 16 + m;
        float av = ASrc[col], dv = ADst[col];
        long r0 = row0 + b * 4;
#pragma unroll
        for (int reg = 0; reg < 4; reg++) {
            out[(r0 + reg) * FOUT + col] = f2fp8(c[reg]);
            sp[reg] += c[reg] * av;
            dp[reg] += c[reg] * dv;
        }
        if ((nt % NTH) == NTH - 1) {  // head boundary: reduce over 16 m-lanes
#pragma unroll
            for (int o = 1; o < 16; o <<= 1) {
#pragma unroll
                for (int reg = 0; reg < 4; reg++) {
                    sp[reg] += __shfl_xor(sp[reg], o, 64);
                    dp[reg] += __shfl_xor(dp[reg], o, 64);
                }
            }
            int hd = nt / NTH;
#pragma unroll
            for (int reg = 0; reg < 4; reg++) {
                if (m == hd) { sk[reg] = sp[reg]; dk[reg] = dp[reg]; }
                sp[reg] = 0.f; dp[reg] = 0.f;
            }
        }
    }
    if (m < HEADS) {
        long r0 = row0 + b * 4;
#pragma unroll
        for (int reg = 0; reg < 4; reg++) {
            s_out_g[(r0 + reg) * HEADS + m] = sk[reg];
            d_out_g[(r0 + reg) * HEADS + m] = dk[reg];
        }
    }
}

// ---- mega kernel: gemm1 FIRST (782 blocks) + edge count behind (3125
// cheap atomic blocks). Intra-kernel fusion = the only concurrency on a
// single stream. Count records rank so the later scatter is atomic-free. ----
__global__ __launch_bounds__(256) void k_mega1(
        const float* __restrict__ x, const uint4* __restrict__ wpk,
        const float* __restrict__ asrc1, const float* __restrict__ adst1,
        unsigned char* __restrict__ u_h, float* __restrict__ f_s,
        float* __restrict__ f_d, const int* __restrict__ ei,
        int* __restrict__ counts, int* __restrict__ rank) {
    if (blockIdx.x < GEMM_GRID) {
        gemm_body<IN_CH, F1, false>(x, wpk, asrc1, adst1, u_h, f_s, f_d,
                                    N_NODES, blockIdx.x);
    } else {
        int e = (blockIdx.x - GEMM_GRID) * 256 + threadIdx.x;
        if (e < N_EDGES) {
            int dst = ei[N_EDGES + e];
            rank[e] = atomicAdd(&counts[dst], 1);
        }
    }
}

__global__ __launch_bounds__(256) void k_gemm2(
        const ushortT* __restrict__ A, const uint4* __restrict__ wpk2,
        const float* __restrict__ asrc2, const float* __restrict__ adst2,
        unsigned char* __restrict__ u_h, float* __restrict__ f_s,
        float* __restrict__ f_d) {
    gemm_body<F1, F2, true>(A, wpk2, asrc2, adst2, u_h, f_s, f_d,
                            N_NODES, blockIdx.x);
}

// ---- 2-phase exclusive scan (consumers add bbase inline) ----
__global__ void k_scan1(const int* __restrict__ counts, int* __restrict__ offs,
                        int* __restrict__ bsum) {
    __shared__ int sh[SCAN_B];
    int b = blockIdx.x, t = threadIdx.x;
    int i = b * SCAN_B + t;
    int v = (i < N_NODES) ? counts[i] : 0;
    sh[t] = v;
    __syncthreads();
    for (int o = 1; o < SCAN_B; o <<= 1) {
        int add = (t >= o) ? sh[t - o] : 0;
        __syncthreads();
        sh[t] += add;
        __syncthreads();
    }
    if (i < N_NODES) offs[i] = sh[t] - v;  // block-local exclusive
    if (t == SCAN_B - 1) bsum[b] = sh[t];
}

__global__ void k_scan2(const int* __restrict__ bsum, int* __restrict__ bbase,
                        int* __restrict__ offs, const int* __restrict__ batch,
                        int* __restrict__ bounds) {
    __shared__ int sh[SCAN_B];
    int t = threadIdx.x;
    int v = (t < SCAN_NB) ? bsum[t] : 0;
    sh[t] = v;
    __syncthreads();
    for (int o = 1; o < SCAN_B; o <<= 1) {
        int add = (t >= o) ? sh[t - o] : 0;
        __syncthreads();
        sh[t] += add;
        __syncthreads();
    }
    if (t < SCAN_NB) bbase[t] = sh[t] - v;      // exclusive base per block
    if (t == SCAN_B - 1) offs[N_NODES] = sh[t]; // grand total (= N_EDGES)
    // fused: graph boundaries via binary search on sorted batch
    if (t <= N_GRAPHS) {
        int lo = 0, hi = N_NODES;
        while (lo < hi) {
            int mid = (lo + hi) >> 1;
            if (batch[mid] < t) lo = mid + 1; else hi = mid;
        }
        bounds[t] = lo;
    }
}

// ---- scatter: ATOMIC-FREE (rank precomputed during count) ----
__global__ void k_scatter(const int* __restrict__ ei, const int* __restrict__ offs,
                          const int* __restrict__ bbase, const int* __restrict__ rank,
                          int* __restrict__ csr_src) {
    int e = blockIdx.x * blockDim.x + threadIdx.x;
    if (e >= N_EDGES) return;
    int src = ei[e], dst = ei[N_EDGES + e];
    int pos = offs[dst] + bbase[dst >> 8] + rank[e];
    csr_src[pos] = src;
}

// ---- fused segment-softmax + aggregation: FOUR nodes per wave (16 lanes
// each), no barriers. Mean degree 16: the r2->r3 lever (fewer wave-
// instructions per edge) applied again — each phase-2 iteration now serves
// 4 edges. VEC=16 (L1) / 8 (L2) keeps per-lane gathers at 16B/8B. CHUNK=64
// keeps LDS at 20KB/block (same occupancy as the 2-node r10 version). ----
template <int C, int VEC, int WPB, int CHUNK>
__global__ __launch_bounds__(64 * WPB) void k_agg(
        const unsigned char* __restrict__ hb, const float* __restrict__ s,
        const float* __restrict__ d, const int* __restrict__ offs,
        const int* __restrict__ bbase, const int* __restrict__ csr_src,
        const float* __restrict__ bias, ushortT* __restrict__ xout) {
    constexpr int F = HEADS * C;
    constexpr int TPN = F / VEC;  // lanes per node
    static_assert(TPN == 16, "four nodes per wave");
    static_assert(C / VEC == 4, "head = tl>>2");
    static_assert(N_NODES % (WPB * 4) == 0, "exact grid");
    __shared__ int lsrc[WPB][4][CHUNK];
    __shared__ float lex[WPB][4][CHUNK * HEADS];
    int wv = threadIdx.x >> 6;
    int t = threadIdx.x & 63;
    int q = t >> 4, tl = t & 15;
    int n = (blockIdx.x * WPB + wv) * 4 + q;
    int h = tl >> 2;
    int beg = offs[n] + bbase[n >> 8];
    int np1 = n + 1;
    int end = (np1 < N_NODES) ? offs[np1] + bbase[np1 >> 8] : offs[N_NODES];
    float4 dn = *(const float4*)(d + n * 4);

    // implicit self-loop: init sumex/acc from own s,d,h (outside the hot loop)
    float4 svn = *(const float4*)(s + n * 4);
    float ssel = (h == 0) ? svn.x : (h == 1) ? svn.y : (h == 2) ? svn.z : svn.w;
    float dsel = (h == 0) ? dn.x : (h == 1) ? dn.y : (h == 2) ? dn.z : dn.w;
    float es = ssel + dsel; es = es > 0.f ? es : 0.2f * es;
    float exs = __expf(es);
    float sumex = exs;
    float acc[VEC];
#pragma unroll
    for (int j = 0; j < VEC; j++) acc[j] = 0.f;
    if (VEC == 16) {
        uint4 w = ((const uint4*)hb)[(long)n * TPN + tl];
        fp8x4_acc(w.x, exs, acc);      fp8x4_acc(w.y, exs, acc + 4);
        fp8x4_acc(w.z, exs, acc + 8);  fp8x4_acc(w.w, exs, acc + 12);
    } else {
        uint2 w = ((const uint2*)hb)[(long)n * TPN + tl];
        fp8x4_acc(w.x, exs, acc);      fp8x4_acc(w.y, exs, acc + 4);
    }

    int tot = end - beg;                       // uniform within a quarter
    int m1 = max(tot, __shfl_xor(tot, 16, 64));
    int maxTot = max(m1, __shfl_xor(m1, 32, 64));  // max over 4 nodes
    for (int base = 0; base < maxTot; base += CHUNK) {
        int cnt = min(CHUNK, tot - base); if (cnt < 0) cnt = 0;
        int cntW = min(CHUNK, maxTot - base);  // wave-uniform loop bound
        // phase 1: each quarter stages its own node's edges (16 lanes)
        for (int i = tl; i < cnt; i += TPN) {
            int sn = csr_src[beg + base + i];
            lsrc[wv][q][i] = sn;
            float4 sv = *(const float4*)(s + sn * 4);
            float e0 = sv.x + dn.x; e0 = e0 > 0.f ? e0 : 0.2f * e0;
            float e1 = sv.y + dn.y; e1 = e1 > 0.f ? e1 : 0.2f * e1;
            float e2 = sv.z + dn.z; e2 = e2 > 0.f ? e2 : 0.2f * e2;
            float e3 = sv.w + dn.w; e3 = e3 > 0.f ? e3 : 0.2f * e3;
            float4 exv = { __expf(e0), __expf(e1), __expf(e2), __expf(e3) };
            *(float4*)&lex[wv][q][i * 4] = exv;
        }
        // intra-wave LDS write->read ordering (no block barrier needed)
        asm volatile("s_waitcnt lgkmcnt(0)" ::: "memory");
        // phase 2: all quarters accumulate in lockstep; shorter nodes padded
        // with ex=0 / sn=0 (branchless, finite data -> adds exact 0)
#pragma unroll 4
        for (int i = 0; i < cntW; i++) {
            bool act = i < cnt;
            float ex = act ? lex[wv][q][i * 4 + h] : 0.f;
            int sn = act ? lsrc[wv][q][i] : 0;
            sumex += ex;
            if (VEC == 16) {
                uint4 w = ((const uint4*)hb)[(long)sn * TPN + tl];
                fp8x4_acc(w.x, ex, acc);      fp8x4_acc(w.y, ex, acc + 4);
                fp8x4_acc(w.z, ex, acc + 8);  fp8x4_acc(w.w, ex, acc + 12);
            } else {
                uint2 w = ((const uint2*)hb)[(long)sn * TPN + tl];
                fp8x4_acc(w.x, ex, acc);      fp8x4_acc(w.y, ex, acc + 4);
            }
        }
        asm volatile("" ::: "memory");
    }
    float inv = 1.f / (sumex + 1e-16f);
    float o[VEC];
#pragma unroll
    for (int j = 0; j < VEC; j++)
        o[j] = fmaxf(acc[j] * inv + bias[tl * VEC + j], 0.f);
    if (VEC == 16) {
        uint4 pk0, pk1;
        pk0.x = (uintT)f2bf(o[0])  | ((uintT)f2bf(o[1])  << 16);
        pk0.y = (uintT)f2bf(o[2])  | ((uintT)f2bf(o[3])  << 16);
        pk0.z = (uintT)f2bf(o[4])  | ((uintT)f2bf(o[5])  << 16);
        pk0.w = (uintT)f2bf(o[6])  | ((uintT)f2bf(o[7])  << 16);
        pk1.x = (uintT)f2bf(o[8])  | ((uintT)f2bf(o[9])  << 16);
        pk1.y = (uintT)f2bf(o[10]) | ((uintT)f2bf(o[11]) << 16);
        pk1.z = (uintT)f2bf(o[12]) | ((uintT)f2bf(o[13]) << 16);
        pk1.w = (uintT)f2bf(o[14]) | ((uintT)f2bf(o[15]) << 16);
        long u4base = ((long)n * TPN + tl) * 2;  // 32B per lane
        ((uint4*)xout)[u4base + 0] = pk0;
        ((uint4*)xout)[u4base + 1] = pk1;
    } else {
        uint4 pk;
        pk.x = (uintT)f2bf(o[0]) | ((uintT)f2bf(o[1]) << 16);
        pk.y = (uintT)f2bf(o[2]) | ((uintT)f2bf(o[3]) << 16);
        pk.z = (uintT)f2bf(o[4]) | ((uintT)f2bf(o[5]) << 16);
        pk.w = (uintT)f2bf(o[6]) | ((uintT)f2bf(o[7]) << 16);
        ((uint4*)xout)[(long)n * TPN + tl] = pk;
    }
}

// ---- pool partials over bf16 x2: block (g,s) sums a contiguous slice ----
__global__ void k_pool_partial(const ushortT* __restrict__ x2, const int* __restrict__ bounds,
                               float* __restrict__ partial) {
    int g = blockIdx.x, s = blockIdx.y;
    int t = threadIdx.x;  // F2 threads
    int n0 = bounds[g], n1 = bounds[g + 1];
    int len = n1 - n0;
    int a = n0 + (int)((long)len * s / POOL_SPLITS);
    int b = n0 + (int)((long)len * (s + 1) / POOL_SPLITS);
    float acc = 0.f;
    for (int n = a; n < b; n++) acc += bf_lo((uintT)x2[(long)n * F2 + t]);
    partial[((long)g * POOL_SPLITS + s) * F2 + t] = acc;
}

// ---- head: block per graph — reduce partials, mean, logits, softmax ----
__global__ void k_head(const float* __restrict__ partial, const int* __restrict__ bounds,
                       const float* __restrict__ Wout, const float* __restrict__ bout,
                       float* __restrict__ out) {
    __shared__ float red0[F2], red1[F2];
    int g = blockIdx.x;
    int t = threadIdx.x;
    int cntN = bounds[g + 1] - bounds[g];
    float cnt = fmaxf((float)cntN, 1.0f);
    float sum = 0.f;
    for (int s = 0; s < POOL_SPLITS; s++)
        sum += partial[((long)g * POOL_SPLITS + s) * F2 + t];
    float p = sum / cnt;
    red0[t] = p * Wout[t * 2 + 0];
    red1[t] = p * Wout[t * 2 + 1];
    __syncthreads();
    for (int off = F2 / 2; off > 0; off >>= 1) {
        if (t < off) { red0[t] += red0[t + off]; red1[t] += red1[t + off]; }
        __syncthreads();
    }
    if (t == 0) {
        float l0 = red0[0] + bout[0];
        float l1 = red1[0] + bout[1];
        float m = fmaxf(l0, l1);
        float e0 = __expf(l0 - m), e1 = __expf(l1 - m);
        float inv = 1.f / (e0 + e1);
        out[g * 2 + 0] = e0 * inv;
        out[g * 2 + 1] = e1 * inv;
    }
}

extern "C" void kernel_launch(void* const* d_in, const int* in_sizes, int n_in,
                              void* d_out, int out_size, void* d_ws, size_t ws_size,
                              hipStream_t stream) {
    const float* x     = (const float*)d_in[0];
    const int*   ei    = (const int*)d_in[1];
    const int*   batch = (const int*)d_in[2];
    const float* W1    = (const float*)d_in[3];
    const float* asrc1 = (const float*)d_in[4];
    const float* adst1 = (const float*)d_in[5];
    const float* b1    = (const float*)d_in[6];
    const float* W2    = (const float*)d_in[7];
    const float* asrc2 = (const float*)d_in[8];
    const float* adst2 = (const float*)d_in[9];
    const float* b2    = (const float*)d_in[10];
    const float* Wout  = (const float*)d_in[11];
    const float* bout  = (const float*)d_in[12];

    char* ws = (char*)d_ws;
    size_t off = 0;
    auto alloc = [&](size_t bytes) -> void* {
        void* p = ws + off;
        off += (bytes + 255) / 256 * 256;
        return p;
    };
    unsigned char* u_h = (unsigned char*)alloc((size_t)N_NODES * F1);  // fp8 h (both layers)
    ushortT* u_x1  = (ushortT*)alloc(sizeof(ushortT) * (size_t)N_NODES * F1);
    ushortT* u_x2  = (ushortT*)alloc(sizeof(ushortT) * (size_t)N_NODES * F2);
    uint4*   wpk   = (uint4*)alloc(sizeof(uint4) * 8192);  // W1|W2 fragment images
    float*   f_s   = (float*)alloc(sizeof(float) * (size_t)N_NODES * HEADS);
    float*   f_d   = (float*)alloc(sizeof(float) * (size_t)N_NODES * HEADS);
    int*     i_cnt = (int*)alloc(sizeof(int) * (size_t)N_NODES);
    int*     i_off = (int*)alloc(sizeof(int) * (size_t)(N_NODES + 1));
    int*     i_rnk = (int*)alloc(sizeof(int) * (size_t)N_EDGES);
    int*     i_csr = (int*)alloc(sizeof(int) * (size_t)N_EDGES);
    int*     i_bnd = (int*)alloc(sizeof(int) * (size_t)(N_GRAPHS + 1));
    int*     i_bs  = (int*)alloc(sizeof(int) * SCAN_NB);
    int*     i_bb  = (int*)alloc(sizeof(int) * SCAN_NB);
    float*   f_prt = (float*)alloc(sizeof(float) * (size_t)N_GRAPHS * POOL_SPLITS * F2);
    (void)ws_size; (void)in_sizes; (void)n_in; (void)out_size;

    // tiny W-only pack + fused i_cnt zeroing
    k_packw<<<32, 256, 0, stream>>>(W1, W2, wpk, i_cnt);

    // mega: gemm1 (782 blocks, 1 tile/wave) + CSR count-with-rank behind
    k_mega1<<<GEMM_GRID + COUNT_GRID, 256, 0, stream>>>(
        x, wpk, asrc1, adst1, u_h, f_s, f_d, ei, i_cnt, i_rnk);

    // 2-phase scan (+bounds); atomic-free scatter using precomputed ranks
    k_scan1<<<SCAN_NB, SCAN_B, 0, stream>>>(i_cnt, i_off, i_bs);
    k_scan2<<<1, SCAN_B, 0, stream>>>(i_bs, i_bb, i_off, batch, i_bnd);
    k_scatter<<<COUNT_GRID, 256, 0, stream>>>(ei, i_off, i_bb, i_rnk, i_csr);

    int agg_grid = N_NODES / (4 * 4);  // 4 nodes/wave, 4 waves/block = 3125

    // Layer 1 aggregation (fp8 gather, 4 nodes per wave, VEC=16)
    k_agg<HID, 16, 4, 64><<<agg_grid, 256, 0, stream>>>(
        u_h, f_s, f_d, i_off, i_bb, i_csr, b1, u_x1);

    // Layer 2
    k_gemm2<<<GEMM_GRID, 256, 0, stream>>>(u_x1, wpk + 4096, asrc2, adst2,
                                           u_h, f_s, f_d);
    k_agg<OUT_CH, 8, 4, 64><<<agg_grid, 256, 0, stream>>>(
        u_h, f_s, f_d, i_off, i_bb, i_csr, b2, u_x2);

    // Pool (1024 blocks, machine-filling) + tiny head
    dim3 pgrid(N_GRAPHS, POOL_SPLITS);
    k_pool_partial<<<pgrid, F2, 0, stream>>>(u_x2, i_bnd, f_prt);
    k_head<<<N_GRAPHS, F2, 0, stream>>>(f_prt, i_bnd, Wout, bout, (float*)d_out);
}

// Round 13
// 246.568 us; speedup vs baseline: 1.2784x; 1.0241x over previous
//
#include <hip/hip_runtime.h>
#include <hip/hip_bf16.h>

#define N_NODES 50000
#define N_EDGES 800000
#define N_GRAPHS 64
#define HEADS 4
#define IN_CH 128
#define HID 64
#define F1 256  // HEADS*HID
#define OUT_CH 32
#define F2 128  // HEADS*OUT_CH
#define POOL_SPLITS 16
#define SCAN_B 256
#define SCAN_NB ((N_NODES + SCAN_B - 1) / SCAN_B)  // 196
#define GEMM_GRID ((N_NODES + 63) / 64)            // 782 (64 rows/block, 1 tile/wave)
#define COUNT_GRID ((N_EDGES + 255) / 256)         // 3125
#define SCATTER_GRID ((N_EDGES / 4 + 255) / 256)   // 782 (4 edges/thread)

typedef unsigned short ushortT;
typedef unsigned int uintT;
typedef short v8s __attribute__((ext_vector_type(8)));
typedef float v4f __attribute__((ext_vector_type(4)));
typedef float v2f __attribute__((ext_vector_type(2)));

__device__ __forceinline__ ushortT f2bf(float f) {
    union { float f; unsigned int i; } v; v.f = f;
    unsigned int x = v.i;
    unsigned int r = (x + 0x7fffu + ((x >> 16) & 1u)) >> 16;  // RNE
    return (ushortT)r;
}
__device__ __forceinline__ float bf_lo(uintT w) {
    union { unsigned int i; float f; } v; v.i = w << 16; return v.f;
}
__device__ __forceinline__ float bf_hi(uintT w) {
    union { unsigned int i; float f; } v; v.i = w & 0xffff0000u; return v.f;
}
// fp8 e4m3 (OCP on gfx950) via HW converts
__device__ __forceinline__ unsigned char f2fp8(float f) {
    return (unsigned char)__builtin_amdgcn_cvt_pk_fp8_f32(f, f, 0u, false);
}
// accumulate 4 fp8 (one u32) scaled by ex into acc[0..3]
__device__ __forceinline__ void fp8x4_acc(uintT w, float ex, float* acc) {
    v2f p0 = __builtin_amdgcn_cvt_pk_f32_fp8(w, false);
    v2f p1 = __builtin_amdgcn_cvt_pk_f32_fp8(w, true);
    acc[0] += ex * p0.x; acc[1] += ex * p0.y;
    acc[2] += ex * p1.x; acc[3] += ex * p1.y;
}

// ---- one-time weight pack into bf16 B-fragment image + fused i_cnt zeroing
// (r11 lesson: no cross-block fence fusion — per-block __threadfence is an
// L2-writeback storm. Launches ~2us; keep stages as separate kernels.) ----
__device__ __forceinline__ void packW_one(const float* __restrict__ W,
                                          uint4* __restrict__ dst,
                                          int i, int FIN, int FOUT) {
    int KC = FIN / 32;
    int lane = i & 63, g = i >> 6;
    int kc = g % KC, nt = g / KC;
    int n = nt * 16 + (lane & 15);
    int kbase = kc * 32 + (lane >> 4) * 8;
    union { uint4 q; ushortT u[8]; } pk;
#pragma unroll
    for (int j = 0; j < 8; j++) pk.u[j] = f2bf(W[(kbase + j) * FOUT + n]);
    dst[i] = pk.q;
}

__global__ __launch_bounds__(256) void k_packw(
        const float* __restrict__ W1, const float* __restrict__ W2,
        uint4* __restrict__ wpk, int* __restrict__ counts) {
    int i = blockIdx.x * 256 + threadIdx.x;  // 8192 = 4096 (W1) + 4096 (W2)
    if (i < 4096) packW_one(W1, wpk, i, IN_CH, F1);
    else          packW_one(W2, wpk + 4096, i - 4096, F1, F2);
    for (int j = i; j < N_NODES; j += 8192) counts[j] = 0;  // fused memset
}

// ---- MFMA GEMM, 64-row block, ONE 16-row tile per wave (r10 measured
// best shape). W image stays L2-resident, no LDS. ----
template <int FIN, int FOUT, bool ABF16>
__device__ __forceinline__ void gemm_body(const void* __restrict__ A,
                                          const uint4* __restrict__ Wpk,
                                          const float* __restrict__ ASrc,
                                          const float* __restrict__ ADst,
                                          unsigned char* __restrict__ out,
                                          float* __restrict__ s_out_g,
                                          float* __restrict__ d_out_g,
                                          int nrows, int bid) {
    constexpr int KC = FIN / 32;
    constexpr int NT = FOUT / 16;
    constexpr int NTH = (FOUT / HEADS) / 16;  // nt tiles per head
    int tid = threadIdx.x;
    int wave = tid >> 6, lane = tid & 63;
    long row0 = (long)bid * 64 + wave * 16;
    if (row0 >= nrows) return;  // wave-uniform (nrows % 16 == 0)
    int m = lane & 15, b = lane >> 4;

    v8s af[KC];
    if (ABF16) {
        const ushortT* Ab = (const ushortT*)A;
#pragma unroll
        for (int kc = 0; kc < KC; kc++) {
            union { v8s v; uint4 q; } u;
            u.q = *(const uint4*)(Ab + (row0 + m) * FIN + kc * 32 + b * 8);
            af[kc] = u.v;
        }
    } else {
        const float* Af = (const float*)A;
#pragma unroll
        for (int kc = 0; kc < KC; kc++) {
            union { v8s v; ushortT u[8]; } u;
            const float* p = Af + (row0 + m) * FIN + kc * 32 + b * 8;
#pragma unroll
            for (int j = 0; j < 8; j++) u.u[j] = f2bf(p[j]);
            af[kc] = u.v;
        }
    }

    float sp[4] = {0,0,0,0}, dp[4] = {0,0,0,0};
    float sk[4], dk[4];
#pragma unroll
    for (int nt = 0; nt < NT; nt++) {
        v4f c = {0.f, 0.f, 0.f, 0.f};
#pragma unroll
        for (int kc = 0; kc < KC; kc++) {
            union { v8s v; uint4 q; } bu;
            bu.q = Wpk[(nt * KC + kc) * 64 + lane];
            c = __builtin_amdgcn_mfma_f32_16x16x32_bf16(af[kc], bu.v, c, 0, 0, 0);
        }
        // C/D: col = lane&15, row = (lane>>4)*4 + reg   [measured m89/m91]
        int col = nt * 16 + m;
        float av = ASrc[col], dv = ADst[col];
        long r0 = row0 + b * 4;
#pragma unroll
        for (int reg = 0; reg < 4; reg++) {
            out[(r0 + reg) * FOUT + col] = f2fp8(c[reg]);
            sp[reg] += c[reg] * av;
            dp[reg] += c[reg] * dv;
        }
        if ((nt % NTH) == NTH - 1) {  // head boundary: reduce over 16 m-lanes
#pragma unroll
            for (int o = 1; o < 16; o <<= 1) {
#pragma unroll
                for (int reg = 0; reg < 4; reg++) {
                    sp[reg] += __shfl_xor(sp[reg], o, 64);
                    dp[reg] += __shfl_xor(dp[reg], o, 64);
                }
            }
            int hd = nt / NTH;
#pragma unroll
            for (int reg = 0; reg < 4; reg++) {
                if (m == hd) { sk[reg] = sp[reg]; dk[reg] = dp[reg]; }
                sp[reg] = 0.f; dp[reg] = 0.f;
            }
        }
    }
    if (m < HEADS) {
        long r0 = row0 + b * 4;
#pragma unroll
        for (int reg = 0; reg < 4; reg++) {
            s_out_g[(r0 + reg) * HEADS + m] = sk[reg];
            d_out_g[(r0 + reg) * HEADS + m] = dk[reg];
        }
    }
}

// ---- mega kernel: gemm1 FIRST (782 blocks) + edge count behind (3125
// cheap atomic blocks). Count's returning atomics are at the device
// coherent-point service-rate floor (~7/cycle device-wide, measured across
// 7 structural variants); gemm1 rides free inside it. ----
__global__ __launch_bounds__(256) void k_mega1(
        const float* __restrict__ x, const uint4* __restrict__ wpk,
        const float* __restrict__ asrc1, const float* __restrict__ adst1,
        unsigned char* __restrict__ u_h, float* __restrict__ f_s,
        float* __restrict__ f_d, const int* __restrict__ ei,
        int* __restrict__ counts, int* __restrict__ rank) {
    if (blockIdx.x < GEMM_GRID) {
        gemm_body<IN_CH, F1, false>(x, wpk, asrc1, adst1, u_h, f_s, f_d,
                                    N_NODES, blockIdx.x);
    } else {
        int e = (blockIdx.x - GEMM_GRID) * 256 + threadIdx.x;
        if (e < N_EDGES) {
            int dst = ei[N_EDGES + e];
            rank[e] = atomicAdd(&counts[dst], 1);
        }
    }
}

__global__ __launch_bounds__(256) void k_gemm2(
        const ushortT* __restrict__ A, const uint4* __restrict__ wpk2,
        const float* __restrict__ asrc2, const float* __restrict__ adst2,
        unsigned char* __restrict__ u_h, float* __restrict__ f_s,
        float* __restrict__ f_d) {
    gemm_body<F1, F2, true>(A, wpk2, asrc2, adst2, u_h, f_s, f_d,
                            N_NODES, blockIdx.x);
}

// ---- 2-phase exclusive scan (consumers add bbase inline) ----
__global__ void k_scan1(const int* __restrict__ counts, int* __restrict__ offs,
                        int* __restrict__ bsum) {
    __shared__ int sh[SCAN_B];
    int b = blockIdx.x, t = threadIdx.x;
    int i = b * SCAN_B + t;
    int v = (i < N_NODES) ? counts[i] : 0;
    sh[t] = v;
    __syncthreads();
    for (int o = 1; o < SCAN_B; o <<= 1) {
        int add = (t >= o) ? sh[t - o] : 0;
        __syncthreads();
        sh[t] += add;
        __syncthreads();
    }
    if (i < N_NODES) offs[i] = sh[t] - v;  // block-local exclusive
    if (t == SCAN_B - 1) bsum[b] = sh[t];
}

__global__ void k_scan2(const int* __restrict__ bsum, int* __restrict__ bbase,
                        int* __restrict__ offs, const int* __restrict__ batch,
                        int* __restrict__ bounds) {
    __shared__ int sh[SCAN_B];
    int t = threadIdx.x;
    int v = (t < SCAN_NB) ? bsum[t] : 0;
    sh[t] = v;
    __syncthreads();
    for (int o = 1; o < SCAN_B; o <<= 1) {
        int add = (t >= o) ? sh[t - o] : 0;
        __syncthreads();
        sh[t] += add;
        __syncthreads();
    }
    if (t < SCAN_NB) bbase[t] = sh[t] - v;      // exclusive base per block
    if (t == SCAN_B - 1) offs[N_NODES] = sh[t]; // grand total (= N_EDGES)
    // fused: graph boundaries via binary search on sorted batch
    if (t <= N_GRAPHS) {
        int lo = 0, hi = N_NODES;
        while (lo < hi) {
            int mid = (lo + hi) >> 1;
            if (batch[mid] < t) lo = mid + 1; else hi = mid;
        }
        bounds[t] = lo;
    }
}

// ---- scatter: ATOMIC-FREE, 4 edges/thread (int4 loads). Each lane runs 4
// independent gather->store chains: the MLP lever that fixed agg (r3/r12),
// applied to this latency-bound kernel. N_EDGES%4==0. ----
__global__ __launch_bounds__(256) void k_scatter(
        const int* __restrict__ ei, const int* __restrict__ offs,
        const int* __restrict__ bbase, const int* __restrict__ rank,
        int* __restrict__ csr_src) {
    int e4 = (blockIdx.x * 256 + threadIdx.x) * 4;
    if (e4 >= N_EDGES) return;
    int4 src = *(const int4*)(ei + e4);
    int4 dst = *(const int4*)(ei + N_EDGES + e4);
    int4 rk  = *(const int4*)(rank + e4);
    csr_src[offs[dst.x] + bbase[dst.x >> 8] + rk.x] = src.x;
    csr_src[offs[dst.y] + bbase[dst.y >> 8] + rk.y] = src.y;
    csr_src[offs[dst.z] + bbase[dst.z >> 8] + rk.z] = src.z;
    csr_src[offs[dst.w] + bbase[dst.w >> 8] + rk.w] = src.w;
}

// ---- fused segment-softmax + aggregation: FOUR nodes per wave (16 lanes
// each), no barriers (r12 measured best). ----
template <int C, int VEC, int WPB, int CHUNK>
__global__ __launch_bounds__(64 * WPB) void k_agg(
        const unsigned char* __restrict__ hb, const float* __restrict__ s,
        const float* __restrict__ d, const int* __restrict__ offs,
        const int* __restrict__ bbase, const int* __restrict__ csr_src,
        const float* __restrict__ bias, ushortT* __restrict__ xout) {
    constexpr int F = HEADS * C;
    constexpr int TPN = F / VEC;  // lanes per node
    static_assert(TPN == 16, "four nodes per wave");
    static_assert(C / VEC == 4, "head = tl>>2");
    static_assert(N_NODES % (WPB * 4) == 0, "exact grid");
    __shared__ int lsrc[WPB][4][CHUNK];
    __shared__ float lex[WPB][4][CHUNK * HEADS];
    int wv = threadIdx.x >> 6;
    int t = threadIdx.x & 63;
    int q = t >> 4, tl = t & 15;
    int n = (blockIdx.x * WPB + wv) * 4 + q;
    int h = tl >> 2;
    int beg = offs[n] + bbase[n >> 8];
    int np1 = n + 1;
    int end = (np1 < N_NODES) ? offs[np1] + bbase[np1 >> 8] : offs[N_NODES];
    float4 dn = *(const float4*)(d + n * 4);

    // implicit self-loop: init sumex/acc from own s,d,h (outside the hot loop)
    float4 svn = *(const float4*)(s + n * 4);
    float ssel = (h == 0) ? svn.x : (h == 1) ? svn.y : (h == 2) ? svn.z : svn.w;
    float dsel = (h == 0) ? dn.x : (h == 1) ? dn.y : (h == 2) ? dn.z : dn.w;
    float es = ssel + dsel; es = es > 0.f ? es : 0.2f * es;
    float exs = __expf(es);
    float sumex = exs;
    float acc[VEC];
#pragma unroll
    for (int j = 0; j < VEC; j++) acc[j] = 0.f;
    if (VEC == 16) {
        uint4 w = ((const uint4*)hb)[(long)n * TPN + tl];
        fp8x4_acc(w.x, exs, acc);      fp8x4_acc(w.y, exs, acc + 4);
        fp8x4_acc(w.z, exs, acc + 8);  fp8x4_acc(w.w, exs, acc + 12);
    } else {
        uint2 w = ((const uint2*)hb)[(long)n * TPN + tl];
        fp8x4_acc(w.x, exs, acc);      fp8x4_acc(w.y, exs, acc + 4);
    }

    int tot = end - beg;                       // uniform within a quarter
    int m1 = max(tot, __shfl_xor(tot, 16, 64));
    int maxTot = max(m1, __shfl_xor(m1, 32, 64));  // max over 4 nodes
    for (int base = 0; base < maxTot; base += CHUNK) {
        int cnt = min(CHUNK, tot - base); if (cnt < 0) cnt = 0;
        int cntW = min(CHUNK, maxTot - base);  // wave-uniform loop bound
        // phase 1: each quarter stages its own node's edges (16 lanes)
        for (int i = tl; i < cnt; i += TPN) {
            int sn = csr_src[beg + base + i];
            lsrc[wv][q][i] = sn;
            float4 sv = *(const float4*)(s + sn * 4);
            float e0 = sv.x + dn.x; e0 = e0 > 0.f ? e0 : 0.2f * e0;
            float e1 = sv.y + dn.y; e1 = e1 > 0.f ? e1 : 0.2f * e1;
            float e2 = sv.z + dn.z; e2 = e2 > 0.f ? e2 : 0.2f * e2;
            float e3 = sv.w + dn.w; e3 = e3 > 0.f ? e3 : 0.2f * e3;
            float4 exv = { __expf(e0), __expf(e1), __expf(e2), __expf(e3) };
            *(float4*)&lex[wv][q][i * 4] = exv;
        }
        // intra-wave LDS write->read ordering (no block barrier needed)
        asm volatile("s_waitcnt lgkmcnt(0)" ::: "memory");
        // phase 2: all quarters accumulate in lockstep; shorter nodes padded
        // with ex=0 / sn=0 (branchless, finite data -> adds exact 0)
#pragma unroll 4
        for (int i = 0; i < cntW; i++) {
            bool act = i < cnt;
            float ex = act ? lex[wv][q][i * 4 + h] : 0.f;
            int sn = act ? lsrc[wv][q][i] : 0;
            sumex += ex;
            if (VEC == 16) {
                uint4 w = ((const uint4*)hb)[(long)sn * TPN + tl];
                fp8x4_acc(w.x, ex, acc);      fp8x4_acc(w.y, ex, acc + 4);
                fp8x4_acc(w.z, ex, acc + 8);  fp8x4_acc(w.w, ex, acc + 12);
            } else {
                uint2 w = ((const uint2*)hb)[(long)sn * TPN + tl];
                fp8x4_acc(w.x, ex, acc);      fp8x4_acc(w.y, ex, acc + 4);
            }
        }
        asm volatile("" ::: "memory");
    }
    float inv = 1.f / (sumex + 1e-16f);
    float o[VEC];
#pragma unroll
    for (int j = 0; j < VEC; j++)
        o[j] = fmaxf(acc[j] * inv + bias[tl * VEC + j], 0.f);
    if (VEC == 16) {
        uint4 pk0, pk1;
        pk0.x = (uintT)f2bf(o[0])  | ((uintT)f2bf(o[1])  << 16);
        pk0.y = (uintT)f2bf(o[2])  | ((uintT)f2bf(o[3])  << 16);
        pk0.z = (uintT)f2bf(o[4])  | ((uintT)f2bf(o[5])  << 16);
        pk0.w = (uintT)f2bf(o[6])  | ((uintT)f2bf(o[7])  << 16);
        pk1.x = (uintT)f2bf(o[8])  | ((uintT)f2bf(o[9])  << 16);
        pk1.y = (uintT)f2bf(o[10]) | ((uintT)f2bf(o[11]) << 16);
        pk1.z = (uintT)f2bf(o[12]) | ((uintT)f2bf(o[13]) << 16);
        pk1.w = (uintT)f2bf(o[14]) | ((uintT)f2bf(o[15]) << 16);
        long u4base = ((long)n * TPN + tl) * 2;  // 32B per lane
        ((uint4*)xout)[u4base + 0] = pk0;
        ((uint4*)xout)[u4base + 1] = pk1;
    } else {
        uint4 pk;
        pk.x = (uintT)f2bf(o[0]) | ((uintT)f2bf(o[1]) << 16);
        pk.y = (uintT)f2bf(o[2]) | ((uintT)f2bf(o[3]) << 16);
        pk.z = (uintT)f2bf(o[4]) | ((uintT)f2bf(o[5]) << 16);
        pk.w = (uintT)f2bf(o[6]) | ((uintT)f2bf(o[7]) << 16);
        ((uint4*)xout)[(long)n * TPN + tl] = pk;
    }
}

// ---- pool partials over bf16 x2: uint loads (2 ch/lane, G13), 128-thread
// block's two halves stride alternate rows -> 32 partials per graph ----
__global__ void k_pool_partial(const ushortT* __restrict__ x2, const int* __restrict__ bounds,
                               float* __restrict__ partial) {
    int g = blockIdx.x, s = blockIdx.y;
    int t = threadIdx.x;  // 128
    int half = t >> 6, tl = t & 63;
    int n0 = bounds[g], n1 = bounds[g + 1];
    int len = n1 - n0;
    int a = n0 + (int)((long)len * s / POOL_SPLITS);
    int b = n0 + (int)((long)len * (s + 1) / POOL_SPLITS);
    float a0 = 0.f, a1 = 0.f;
    const uintT* x2u = (const uintT*)x2;
    for (int n = a + half; n < b; n += 2) {
        uintT w = x2u[(long)n * 64 + tl];
        a0 += bf_lo(w); a1 += bf_hi(w);
    }
    float2 pr = {a0, a1};
    *(float2*)&partial[(((long)g * 2 * POOL_SPLITS) + (s * 2 + half)) * F2 + 2 * tl] = pr;
}

// ---- head: block per graph — reduce 32 partials, mean, logits, softmax ----
__global__ void k_head(const float* __restrict__ partial, const int* __restrict__ bounds,
                       const float* __restrict__ Wout, const float* __restrict__ bout,
                       float* __restrict__ out) {
    __shared__ float red0[F2], red1[F2];
    int g = blockIdx.x;
    int t = threadIdx.x;
    int cntN = bounds[g + 1] - bounds[g];
    float cnt = fmaxf((float)cntN, 1.0f);
    float sum = 0.f;
    for (int s = 0; s < 2 * POOL_SPLITS; s++)
        sum += partial[((long)g * 2 * POOL_SPLITS + s) * F2 + t];
    float p = sum / cnt;
    red0[t] = p * Wout[t * 2 + 0];
    red1[t] = p * Wout[t * 2 + 1];
    __syncthreads();
    for (int off = F2 / 2; off > 0; off >>= 1) {
        if (t < off) { red0[t] += red0[t + off]; red1[t] += red1[t + off]; }
        __syncthreads();
    }
    if (t == 0) {
        float l0 = red0[0] + bout[0];
        float l1 = red1[0] + bout[1];
        float m = fmaxf(l0, l1);
        float e0 = __expf(l0 - m), e1 = __expf(l1 - m);
        float inv = 1.f / (e0 + e1);
        out[g * 2 + 0] = e0 * inv;
        out[g * 2 + 1] = e1 * inv;
    }
}

extern "C" void kernel_launch(void* const* d_in, const int* in_sizes, int n_in,
                              void* d_out, int out_size, void* d_ws, size_t ws_size,
                              hipStream_t stream) {
    const float* x     = (const float*)d_in[0];
    const int*   ei    = (const int*)d_in[1];
    const int*   batch = (const int*)d_in[2];
    const float* W1    = (const float*)d_in[3];
    const float* asrc1 = (const float*)d_in[4];
    const float* adst1 = (const float*)d_in[5];
    const float* b1    = (const float*)d_in[6];
    const float* W2    = (const float*)d_in[7];
    const float* asrc2 = (const float*)d_in[8];
    const float* adst2 = (const float*)d_in[9];
    const float* b2    = (const float*)d_in[10];
    const float* Wout  = (const float*)d_in[11];
    const float* bout  = (const float*)d_in[12];

    char* ws = (char*)d_ws;
    size_t off = 0;
    auto alloc = [&](size_t bytes) -> void* {
        void* p = ws + off;
        off += (bytes + 255) / 256 * 256;
        return p;
    };
    unsigned char* u_h = (unsigned char*)alloc((size_t)N_NODES * F1);  // fp8 h (both layers)
    ushortT* u_x1  = (ushortT*)alloc(sizeof(ushortT) * (size_t)N_NODES * F1);
    ushortT* u_x2  = (ushortT*)alloc(sizeof(ushortT) * (size_t)N_NODES * F2);
    uint4*   wpk   = (uint4*)alloc(sizeof(uint4) * 8192);  // W1|W2 fragment images
    float*   f_s   = (float*)alloc(sizeof(float) * (size_t)N_NODES * HEADS);
    float*   f_d   = (float*)alloc(sizeof(float) * (size_t)N_NODES * HEADS);
    int*     i_cnt = (int*)alloc(sizeof(int) * (size_t)N_NODES);
    int*     i_off = (int*)alloc(sizeof(int) * (size_t)(N_NODES + 1));
    int*     i_rnk = (int*)alloc(sizeof(int) * (size_t)N_EDGES);
    int*     i_csr = (int*)alloc(sizeof(int) * (size_t)N_EDGES);
    int*     i_bnd = (int*)alloc(sizeof(int) * (size_t)(N_GRAPHS + 1));
    int*     i_bs  = (int*)alloc(sizeof(int) * SCAN_NB);
    int*     i_bb  = (int*)alloc(sizeof(int) * SCAN_NB);
    float*   f_prt = (float*)alloc(sizeof(float) * (size_t)N_GRAPHS * 2 * POOL_SPLITS * F2);
    (void)ws_size; (void)in_sizes; (void)n_in; (void)out_size;

    // tiny W-only pack + fused i_cnt zeroing
    k_packw<<<32, 256, 0, stream>>>(W1, W2, wpk, i_cnt);

    // mega: gemm1 (782 blocks, 1 tile/wave) + CSR count-with-rank behind
    k_mega1<<<GEMM_GRID + COUNT_GRID, 256, 0, stream>>>(
        x, wpk, asrc1, adst1, u_h, f_s, f_d, ei, i_cnt, i_rnk);

    // 2-phase scan (+bounds); atomic-free 4-edge/thread scatter
    k_scan1<<<SCAN_NB, SCAN_B, 0, stream>>>(i_cnt, i_off, i_bs);
    k_scan2<<<1, SCAN_B, 0, stream>>>(i_bs, i_bb, i_off, batch, i_bnd);
    k_scatter<<<SCATTER_GRID, 256, 0, stream>>>(ei, i_off, i_bb, i_rnk, i_csr);

    int agg_grid = N_NODES / (4 * 4);  // 4 nodes/wave, 4 waves/block = 3125

    // Layer 1 aggregation (fp8 gather, 4 nodes per wave, VEC=16)
    k_agg<HID, 16, 4, 64><<<agg_grid, 256, 0, stream>>>(
        u_h, f_s, f_d, i_off, i_bb, i_csr, b1, u_x1);

    // Layer 2
    k_gemm2<<<GEMM_GRID, 256, 0, stream>>>(u_x1, wpk + 4096, asrc2, adst2,
                                           u_h, f_s, f_d);
    k_agg<OUT_CH, 8, 4, 64><<<agg_grid, 256, 0, stream>>>(
        u_h, f_s, f_d, i_off, i_bb, i_csr, b2, u_x2);

    // Pool (1024 blocks, uint loads, 32 partials/graph) + tiny head
    dim3 pgrid(N_GRAPHS, POOL_SPLITS);
    k_pool_partial<<<pgrid, F2, 0, stream>>>(u_x2, i_bnd, f_prt);
    k_head<<<N_GRAPHS, F2, 0, stream>>>(f_prt, i_bnd, Wout, bout, (float*)d_out);
}

// Round 14
// 237.391 us; speedup vs baseline: 1.3278x; 1.0387x over previous
//
#include <hip/hip_runtime.h>
#include <hip/hip_bf16.h>

#define N_NODES 50000
#define N_EDGES 800000
#define N_GRAPHS 64
#define HEADS 4
#define IN_CH 128
#define HID 64
#define F1 256  // HEADS*HID
#define OUT_CH 32
#define F2 128  // HEADS*OUT_CH
#define POOL_SPLITS 16
#define SCAN_B 256
#define SCAN_NB ((N_NODES + SCAN_B - 1) / SCAN_B)  // 196
#define GEMM_GRID ((N_NODES + 63) / 64)            // 782 (64 rows/block, 1 tile/wave)
#define COUNT_GRID ((N_EDGES + 255) / 256)         // 3125
#define SCATTER_GRID ((N_EDGES / 4 + 255) / 256)   // 782 (4 edges/thread)
#define AGEMM_GRID (N_NODES / 16)                  // 3125 (16 nodes = 1 gemm tile)
#define HPAD 264                                   // 256 + 8 bf16 pad (bank-safe)

typedef unsigned short ushortT;
typedef unsigned int uintT;
typedef short v8s __attribute__((ext_vector_type(8)));
typedef float v4f __attribute__((ext_vector_type(4)));
typedef float v2f __attribute__((ext_vector_type(2)));

__device__ __forceinline__ ushortT f2bf(float f) {
    union { float f; unsigned int i; } v; v.f = f;
    unsigned int x = v.i;
    unsigned int r = (x + 0x7fffu + ((x >> 16) & 1u)) >> 16;  // RNE
    return (ushortT)r;
}
__device__ __forceinline__ float bf_lo(uintT w) {
    union { unsigned int i; float f; } v; v.i = w << 16; return v.f;
}
__device__ __forceinline__ float bf_hi(uintT w) {
    union { unsigned int i; float f; } v; v.i = w & 0xffff0000u; return v.f;
}
// fp8 e4m3 (OCP on gfx950) via HW converts
__device__ __forceinline__ unsigned char f2fp8(float f) {
    return (unsigned char)__builtin_amdgcn_cvt_pk_fp8_f32(f, f, 0u, false);
}
// accumulate 4 fp8 (one u32) scaled by ex into acc[0..3]
__device__ __forceinline__ void fp8x4_acc(uintT w, float ex, float* acc) {
    v2f p0 = __builtin_amdgcn_cvt_pk_f32_fp8(w, false);
    v2f p1 = __builtin_amdgcn_cvt_pk_f32_fp8(w, true);
    acc[0] += ex * p0.x; acc[1] += ex * p0.y;
    acc[2] += ex * p1.x; acc[3] += ex * p1.y;
}

// ---- one-time weight pack into bf16 B-fragment image + fused i_cnt zeroing ----
__device__ __forceinline__ void packW_one(const float* __restrict__ W,
                                          uint4* __restrict__ dst,
                                          int i, int FIN, int FOUT) {
    int KC = FIN / 32;
    int lane = i & 63, g = i >> 6;
    int kc = g % KC, nt = g / KC;
    int n = nt * 16 + (lane & 15);
    int kbase = kc * 32 + (lane >> 4) * 8;
    union { uint4 q; ushortT u[8]; } pk;
#pragma unroll
    for (int j = 0; j < 8; j++) pk.u[j] = f2bf(W[(kbase + j) * FOUT + n]);
    dst[i] = pk.q;
}

__global__ __launch_bounds__(256) void k_packw(
        const float* __restrict__ W1, const float* __restrict__ W2,
        uint4* __restrict__ wpk, int* __restrict__ counts) {
    int i = blockIdx.x * 256 + threadIdx.x;  // 8192 = 4096 (W1) + 4096 (W2)
    if (i < 4096) packW_one(W1, wpk, i, IN_CH, F1);
    else          packW_one(W2, wpk + 4096, i - 4096, F1, F2);
    for (int j = i; j < N_NODES; j += 8192) counts[j] = 0;  // fused memset
}

// ---- MFMA GEMM1, 64-row block, ONE 16-row tile per wave (r10 best shape) ----
__device__ __forceinline__ void gemm1_body(const float* __restrict__ A,
                                           const uint4* __restrict__ Wpk,
                                           const float* __restrict__ ASrc,
                                           const float* __restrict__ ADst,
                                           unsigned char* __restrict__ out,
                                           float* __restrict__ s_out_g,
                                           float* __restrict__ d_out_g,
                                           int bid) {
    constexpr int KC = IN_CH / 32;           // 4
    constexpr int NT = F1 / 16;              // 16
    constexpr int NTH = (F1 / HEADS) / 16;   // 4
    int tid = threadIdx.x;
    int wave = tid >> 6, lane = tid & 63;
    long row0 = (long)bid * 64 + wave * 16;
    if (row0 >= N_NODES) return;
    int m = lane & 15, b = lane >> 4;

    v8s af[KC];
#pragma unroll
    for (int kc = 0; kc < KC; kc++) {
        union { v8s v; ushortT u[8]; } u;
        const float* p = A + (row0 + m) * IN_CH + kc * 32 + b * 8;
#pragma unroll
        for (int j = 0; j < 8; j++) u.u[j] = f2bf(p[j]);
        af[kc] = u.v;
    }

    float sp[4] = {0,0,0,0}, dp[4] = {0,0,0,0};
    float sk[4], dk[4];
#pragma unroll
    for (int nt = 0; nt < NT; nt++) {
        v4f c = {0.f, 0.f, 0.f, 0.f};
#pragma unroll
        for (int kc = 0; kc < KC; kc++) {
            union { v8s v; uint4 q; } bu;
            bu.q = Wpk[(nt * KC + kc) * 64 + lane];
            c = __builtin_amdgcn_mfma_f32_16x16x32_bf16(af[kc], bu.v, c, 0, 0, 0);
        }
        // C/D: col = lane&15, row = (lane>>4)*4 + reg   [measured m89/m91]
        int col = nt * 16 + m;
        float av = ASrc[col], dv = ADst[col];
        long r0 = row0 + b * 4;
#pragma unroll
        for (int reg = 0; reg < 4; reg++) {
            out[(r0 + reg) * F1 + col] = f2fp8(c[reg]);
            sp[reg] += c[reg] * av;
            dp[reg] += c[reg] * dv;
        }
        if ((nt % NTH) == NTH - 1) {  // head boundary: reduce over 16 m-lanes
#pragma unroll
            for (int o = 1; o < 16; o <<= 1) {
#pragma unroll
                for (int reg = 0; reg < 4; reg++) {
                    sp[reg] += __shfl_xor(sp[reg], o, 64);
                    dp[reg] += __shfl_xor(dp[reg], o, 64);
                }
            }
            int hd = nt / NTH;
#pragma unroll
            for (int reg = 0; reg < 4; reg++) {
                if (m == hd) { sk[reg] = sp[reg]; dk[reg] = dp[reg]; }
                sp[reg] = 0.f; dp[reg] = 0.f;
            }
        }
    }
    if (m < HEADS) {
        long r0 = row0 + b * 4;
#pragma unroll
        for (int reg = 0; reg < 4; reg++) {
            s_out_g[(r0 + reg) * HEADS + m] = sk[reg];
            d_out_g[(r0 + reg) * HEADS + m] = dk[reg];
        }
    }
}

// ---- mega kernel: gemm1 FIRST (782 blocks) + edge count behind (3125
// atomic blocks; returning-atomic service rate is the measured ~45us floor
// across 7 structural variants — gemm1 rides free inside it) ----
__global__ __launch_bounds__(256) void k_mega1(
        const float* __restrict__ x, const uint4* __restrict__ wpk,
        const float* __restrict__ asrc1, const float* __restrict__ adst1,
        unsigned char* __restrict__ u_h, float* __restrict__ f_s,
        float* __restrict__ f_d, const int* __restrict__ ei,
        int* __restrict__ counts, int* __restrict__ rank) {
    if (blockIdx.x < GEMM_GRID) {
        gemm1_body(x, wpk, asrc1, adst1, u_h, f_s, f_d, blockIdx.x);
    } else {
        int e = (blockIdx.x - GEMM_GRID) * 256 + threadIdx.x;
        if (e < N_EDGES) {
            int dst = ei[N_EDGES + e];
            rank[e] = atomicAdd(&counts[dst], 1);
        }
    }
}

// ---- 2-phase exclusive scan (consumers add bbase inline) ----
__global__ void k_scan1(const int* __restrict__ counts, int* __restrict__ offs,
                        int* __restrict__ bsum) {
    __shared__ int sh[SCAN_B];
    int b = blockIdx.x, t = threadIdx.x;
    int i = b * SCAN_B + t;
    int v = (i < N_NODES) ? counts[i] : 0;
    sh[t] = v;
    __syncthreads();
    for (int o = 1; o < SCAN_B; o <<= 1) {
        int add = (t >= o) ? sh[t - o] : 0;
        __syncthreads();
        sh[t] += add;
        __syncthreads();
    }
    if (i < N_NODES) offs[i] = sh[t] - v;  // block-local exclusive
    if (t == SCAN_B - 1) bsum[b] = sh[t];
}

__global__ void k_scan2(const int* __restrict__ bsum, int* __restrict__ bbase,
                        int* __restrict__ offs, const int* __restrict__ batch,
                        int* __restrict__ bounds) {
    __shared__ int sh[SCAN_B];
    int t = threadIdx.x;
    int v = (t < SCAN_NB) ? bsum[t] : 0;
    sh[t] = v;
    __syncthreads();
    for (int o = 1; o < SCAN_B; o <<= 1) {
        int add = (t >= o) ? sh[t - o] : 0;
        __syncthreads();
        sh[t] += add;
        __syncthreads();
    }
    if (t < SCAN_NB) bbase[t] = sh[t] - v;      // exclusive base per block
    if (t == SCAN_B - 1) offs[N_NODES] = sh[t]; // grand total (= N_EDGES)
    // fused: graph boundaries via binary search on sorted batch
    if (t <= N_GRAPHS) {
        int lo = 0, hi = N_NODES;
        while (lo < hi) {
            int mid = (lo + hi) >> 1;
            if (batch[mid] < t) lo = mid + 1; else hi = mid;
        }
        bounds[t] = lo;
    }
}

// ---- scatter: ATOMIC-FREE, 4 edges/thread (r13 measured win) ----
__global__ __launch_bounds__(256) void k_scatter(
        const int* __restrict__ ei, const int* __restrict__ offs,
        const int* __restrict__ bbase, const int* __restrict__ rank,
        int* __restrict__ csr_src) {
    int e4 = (blockIdx.x * 256 + threadIdx.x) * 4;
    if (e4 >= N_EDGES) return;
    int4 src = *(const int4*)(ei + e4);
    int4 dst = *(const int4*)(ei + N_EDGES + e4);
    int4 rk  = *(const int4*)(rank + e4);
    csr_src[offs[dst.x] + bbase[dst.x >> 8] + rk.x] = src.x;
    csr_src[offs[dst.y] + bbase[dst.y >> 8] + rk.y] = src.y;
    csr_src[offs[dst.z] + bbase[dst.z >> 8] + rk.z] = src.z;
    csr_src[offs[dst.w] + bbase[dst.w >> 8] + rk.w] = src.w;
}

// ---- FUSED agg(L1) + gemm2: one block = 16 nodes = one gemm2 row-tile.
// Phase A: 4 waves x 4 nodes/wave aggregate (r12 shape, VEC=16) into an LDS
// tile [16][HPAD] bf16 (+8 pad -> 2-way-free ds_read_b128). Phase B: gemm2
// head-split (r4's verified wave=head shape) reads A from LDS. Deletes the
// 38MB u_x1 HBM round-trip + 1 launch, pipelines agg-tail with gemm.
// Outputs go to SEPARATE buffers (h2/s2/d2): other blocks still gather
// layer-1 u_h / f_s / f_d concurrently (no in-place overwrite race).
__global__ __launch_bounds__(256) void k_aggemm(
        const unsigned char* __restrict__ hb, const float* __restrict__ s,
        const float* __restrict__ d, const int* __restrict__ offs,
        const int* __restrict__ bbase, const int* __restrict__ csr_src,
        const float* __restrict__ b1, const uint4* __restrict__ wpk2,
        const float* __restrict__ asrc2, const float* __restrict__ adst2,
        unsigned char* __restrict__ h2, float* __restrict__ s2,
        float* __restrict__ d2) {
    constexpr int CHUNK = 32;   // deg~16 -> 1 chunk; LDS 18.25KB -> 8 blk/CU
    constexpr int TPN = 16;     // 4 nodes per wave (VEC=16)
    __shared__ int lsrc[4][4][CHUNK];
    __shared__ float lex[4][4][CHUNK * HEADS];
    __shared__ ushortT lh[16 * HPAD];
    int wv = threadIdx.x >> 6;
    int t = threadIdx.x & 63;
    int q = t >> 4, tl = t & 15;
    int nloc = wv * 4 + q;
    int n = blockIdx.x * 16 + nloc;
    int h = tl >> 2;
    int beg = offs[n] + bbase[n >> 8];
    int np1 = n + 1;
    int end = (np1 < N_NODES) ? offs[np1] + bbase[np1 >> 8] : offs[N_NODES];
    float4 dn = *(const float4*)(d + n * 4);

    // implicit self-loop
    float4 svn = *(const float4*)(s + n * 4);
    float ssel = (h == 0) ? svn.x : (h == 1) ? svn.y : (h == 2) ? svn.z : svn.w;
    float dsel = (h == 0) ? dn.x : (h == 1) ? dn.y : (h == 2) ? dn.z : dn.w;
    float es = ssel + dsel; es = es > 0.f ? es : 0.2f * es;
    float exs = __expf(es);
    float sumex = exs;
    float acc[16];
#pragma unroll
    for (int j = 0; j < 16; j++) acc[j] = 0.f;
    {
        uint4 w = ((const uint4*)hb)[(long)n * TPN + tl];
        fp8x4_acc(w.x, exs, acc);      fp8x4_acc(w.y, exs, acc + 4);
        fp8x4_acc(w.z, exs, acc + 8);  fp8x4_acc(w.w, exs, acc + 12);
    }

    int tot = end - beg;
    int m1 = max(tot, __shfl_xor(tot, 16, 64));
    int maxTot = max(m1, __shfl_xor(m1, 32, 64));
    for (int base = 0; base < maxTot; base += CHUNK) {
        int cnt = min(CHUNK, tot - base); if (cnt < 0) cnt = 0;
        int cntW = min(CHUNK, maxTot - base);
        for (int i = tl; i < cnt; i += TPN) {
            int sn = csr_src[beg + base + i];
            lsrc[wv][q][i] = sn;
            float4 sv = *(const float4*)(s + sn * 4);
            float e0 = sv.x + dn.x; e0 = e0 > 0.f ? e0 : 0.2f * e0;
            float e1 = sv.y + dn.y; e1 = e1 > 0.f ? e1 : 0.2f * e1;
            float e2 = sv.z + dn.z; e2 = e2 > 0.f ? e2 : 0.2f * e2;
            float e3 = sv.w + dn.w; e3 = e3 > 0.f ? e3 : 0.2f * e3;
            float4 exv = { __expf(e0), __expf(e1), __expf(e2), __expf(e3) };
            *(float4*)&lex[wv][q][i * 4] = exv;
        }
        asm volatile("s_waitcnt lgkmcnt(0)" ::: "memory");
#pragma unroll 4
        for (int i = 0; i < cntW; i++) {
            bool act = i < cnt;
            float ex = act ? lex[wv][q][i * 4 + h] : 0.f;
            int sn = act ? lsrc[wv][q][i] : 0;
            sumex += ex;
            uint4 w = ((const uint4*)hb)[(long)sn * TPN + tl];
            fp8x4_acc(w.x, ex, acc);      fp8x4_acc(w.y, ex, acc + 4);
            fp8x4_acc(w.z, ex, acc + 8);  fp8x4_acc(w.w, ex, acc + 12);
        }
        asm volatile("" ::: "memory");
    }
    float inv = 1.f / (sumex + 1e-16f);
    float o[16];
#pragma unroll
    for (int j = 0; j < 16; j++)
        o[j] = fmaxf(acc[j] * inv + b1[tl * 16 + j], 0.f);
    uint4 pk0, pk1;
    pk0.x = (uintT)f2bf(o[0])  | ((uintT)f2bf(o[1])  << 16);
    pk0.y = (uintT)f2bf(o[2])  | ((uintT)f2bf(o[3])  << 16);
    pk0.z = (uintT)f2bf(o[4])  | ((uintT)f2bf(o[5])  << 16);
    pk0.w = (uintT)f2bf(o[6])  | ((uintT)f2bf(o[7])  << 16);
    pk1.x = (uintT)f2bf(o[8])  | ((uintT)f2bf(o[9])  << 16);
    pk1.y = (uintT)f2bf(o[10]) | ((uintT)f2bf(o[11]) << 16);
    pk1.z = (uintT)f2bf(o[12]) | ((uintT)f2bf(o[13]) << 16);
    pk1.w = (uintT)f2bf(o[14]) | ((uintT)f2bf(o[15]) << 16);
    *(uint4*)&lh[nloc * HPAD + tl * 16]     = pk0;
    *(uint4*)&lh[nloc * HPAD + tl * 16 + 8] = pk1;
    __syncthreads();

    // ---- phase B: gemm2 (16 rows x F2), wave = head, NTH=2, KC=8 ----
    constexpr int KC = F1 / 32;              // 8
    constexpr int NTH2 = (F2 / HEADS) / 16;  // 2
    int wave = wv, lane = t;
    int m = lane & 15, b = lane >> 4;
    long row0 = (long)blockIdx.x * 16;

    v8s af[KC];
#pragma unroll
    for (int kc = 0; kc < KC; kc++) {
        union { v8s v; uint4 q; } u;
        u.q = *(const uint4*)&lh[m * HPAD + kc * 32 + b * 8];
        af[kc] = u.v;
    }

    float sp[4] = {0,0,0,0}, dp[4] = {0,0,0,0};
#pragma unroll
    for (int j = 0; j < NTH2; j++) {
        int nt = wave * NTH2 + j;
        v4f c = {0.f, 0.f, 0.f, 0.f};
#pragma unroll
        for (int kc = 0; kc < KC; kc++) {
            union { v8s v; uint4 q; } bu;
            bu.q = wpk2[(nt * KC + kc) * 64 + lane];
            c = __builtin_amdgcn_mfma_f32_16x16x32_bf16(af[kc], bu.v, c, 0, 0, 0);
        }
        int col = nt * 16 + m;
        float av = asrc2[col], dv = adst2[col];
#pragma unroll
        for (int reg = 0; reg < 4; reg++) {
            h2[(row0 + b * 4 + reg) * F2 + col] = f2fp8(c[reg]);
            sp[reg] += c[reg] * av;
            dp[reg] += c[reg] * dv;
        }
    }
#pragma unroll
    for (int o2 = 1; o2 < 16; o2 <<= 1) {
#pragma unroll
        for (int reg = 0; reg < 4; reg++) {
            sp[reg] += __shfl_xor(sp[reg], o2, 64);
            dp[reg] += __shfl_xor(dp[reg], o2, 64);
        }
    }
    if (m == 0) {
#pragma unroll
        for (int reg = 0; reg < 4; reg++) {
            s2[(row0 + b * 4 + reg) * HEADS + wave] = sp[reg];
            d2[(row0 + b * 4 + reg) * HEADS + wave] = dp[reg];
        }
    }
}

// ---- agg layer 2: FOUR nodes per wave (r12/r13 measured best), VEC=8 ----
template <int C, int VEC, int WPB, int CHUNK>
__global__ __launch_bounds__(64 * WPB) void k_agg(
        const unsigned char* __restrict__ hb, const float* __restrict__ s,
        const float* __restrict__ d, const int* __restrict__ offs,
        const int* __restrict__ bbase, const int* __restrict__ csr_src,
        const float* __restrict__ bias, ushortT* __restrict__ xout) {
    constexpr int F = HEADS * C;
    constexpr int TPN = F / VEC;  // lanes per node
    static_assert(TPN == 16, "four nodes per wave");
    static_assert(C / VEC == 4, "head = tl>>2");
    static_assert(N_NODES % (WPB * 4) == 0, "exact grid");
    __shared__ int lsrc[WPB][4][CHUNK];
    __shared__ float lex[WPB][4][CHUNK * HEADS];
    int wv = threadIdx.x >> 6;
    int t = threadIdx.x & 63;
    int q = t >> 4, tl = t & 15;
    int n = (blockIdx.x * WPB + wv) * 4 + q;
    int h = tl >> 2;
    int beg = offs[n] + bbase[n >> 8];
    int np1 = n + 1;
    int end = (np1 < N_NODES) ? offs[np1] + bbase[np1 >> 8] : offs[N_NODES];
    float4 dn = *(const float4*)(d + n * 4);

    float4 svn = *(const float4*)(s + n * 4);
    float ssel = (h == 0) ? svn.x : (h == 1) ? svn.y : (h == 2) ? svn.z : svn.w;
    float dsel = (h == 0) ? dn.x : (h == 1) ? dn.y : (h == 2) ? dn.z : dn.w;
    float es = ssel + dsel; es = es > 0.f ? es : 0.2f * es;
    float exs = __expf(es);
    float sumex = exs;
    float acc[VEC];
#pragma unroll
    for (int j = 0; j < VEC; j++) acc[j] = 0.f;
    {
        uint2 w = ((const uint2*)hb)[(long)n * TPN + tl];
        fp8x4_acc(w.x, exs, acc);      fp8x4_acc(w.y, exs, acc + 4);
    }

    int tot = end - beg;
    int m1 = max(tot, __shfl_xor(tot, 16, 64));
    int maxTot = max(m1, __shfl_xor(m1, 32, 64));
    for (int base = 0; base < maxTot; base += CHUNK) {
        int cnt = min(CHUNK, tot - base); if (cnt < 0) cnt = 0;
        int cntW = min(CHUNK, maxTot - base);
        for (int i = tl; i < cnt; i += TPN) {
            int sn = csr_src[beg + base + i];
            lsrc[wv][q][i] = sn;
            float4 sv = *(const float4*)(s + sn * 4);
            float e0 = sv.x + dn.x; e0 = e0 > 0.f ? e0 : 0.2f * e0;
            float e1 = sv.y + dn.y; e1 = e1 > 0.f ? e1 : 0.2f * e1;
            float e2 = sv.z + dn.z; e2 = e2 > 0.f ? e2 : 0.2f * e2;
            float e3 = sv.w + dn.w; e3 = e3 > 0.f ? e3 : 0.2f * e3;
            float4 exv = { __expf(e0), __expf(e1), __expf(e2), __expf(e3) };
            *(float4*)&lex[wv][q][i * 4] = exv;
        }
        asm volatile("s_waitcnt lgkmcnt(0)" ::: "memory");
#pragma unroll 4
        for (int i = 0; i < cntW; i++) {
            bool act = i < cnt;
            float ex = act ? lex[wv][q][i * 4 + h] : 0.f;
            int sn = act ? lsrc[wv][q][i] : 0;
            sumex += ex;
            uint2 w = ((const uint2*)hb)[(long)sn * TPN + tl];
            fp8x4_acc(w.x, ex, acc);      fp8x4_acc(w.y, ex, acc + 4);
        }
        asm volatile("" ::: "memory");
    }
    float inv = 1.f / (sumex + 1e-16f);
    float o[VEC];
#pragma unroll
    for (int j = 0; j < VEC; j++)
        o[j] = fmaxf(acc[j] * inv + bias[tl * VEC + j], 0.f);
    uint4 pk;
    pk.x = (uintT)f2bf(o[0]) | ((uintT)f2bf(o[1]) << 16);
    pk.y = (uintT)f2bf(o[2]) | ((uintT)f2bf(o[3]) << 16);
    pk.z = (uintT)f2bf(o[4]) | ((uintT)f2bf(o[5]) << 16);
    pk.w = (uintT)f2bf(o[6]) | ((uintT)f2bf(o[7]) << 16);
    ((uint4*)xout)[(long)n * TPN + tl] = pk;
}

// ---- pool partials over bf16 x2: uint loads, 32 partials/graph (r13) ----
__global__ void k_pool_partial(const ushortT* __restrict__ x2, const int* __restrict__ bounds,
                               float* __restrict__ partial) {
    int g = blockIdx.x, s = blockIdx.y;
    int t = threadIdx.x;  // 128
    int half = t >> 6, tl = t & 63;
    int n0 = bounds[g], n1 = bounds[g + 1];
    int len = n1 - n0;
    int a = n0 + (int)((long)len * s / POOL_SPLITS);
    int b = n0 + (int)((long)len * (s + 1) / POOL_SPLITS);
    float a0 = 0.f, a1 = 0.f;
    const uintT* x2u = (const uintT*)x2;
    for (int n = a + half; n < b; n += 2) {
        uintT w = x2u[(long)n * 64 + tl];
        a0 += bf_lo(w); a1 += bf_hi(w);
    }
    float2 pr = {a0, a1};
    *(float2*)&partial[(((long)g * 2 * POOL_SPLITS) + (s * 2 + half)) * F2 + 2 * tl] = pr;
}

// ---- head: block per graph — reduce 32 partials, mean, logits, softmax ----
__global__ void k_head(const float* __restrict__ partial, const int* __restrict__ bounds,
                       const float* __restrict__ Wout, const float* __restrict__ bout,
                       float* __restrict__ out) {
    __shared__ float red0[F2], red1[F2];
    int g = blockIdx.x;
    int t = threadIdx.x;
    int cntN = bounds[g + 1] - bounds[g];
    float cnt = fmaxf((float)cntN, 1.0f);
    float sum = 0.f;
    for (int s = 0; s < 2 * POOL_SPLITS; s++)
        sum += partial[((long)g * 2 * POOL_SPLITS + s) * F2 + t];
    float p = sum / cnt;
    red0[t] = p * Wout[t * 2 + 0];
    red1[t] = p * Wout[t * 2 + 1];
    __syncthreads();
    for (int off = F2 / 2; off > 0; off >>= 1) {
        if (t < off) { red0[t] += red0[t + off]; red1[t] += red1[t + off]; }
        __syncthreads();
    }
    if (t == 0) {
        float l0 = red0[0] + bout[0];
        float l1 = red1[0] + bout[1];
        float m = fmaxf(l0, l1);
        float e0 = __expf(l0 - m), e1 = __expf(l1 - m);
        float inv = 1.f / (e0 + e1);
        out[g * 2 + 0] = e0 * inv;
        out[g * 2 + 1] = e1 * inv;
    }
}

extern "C" void kernel_launch(void* const* d_in, const int* in_sizes, int n_in,
                              void* d_out, int out_size, void* d_ws, size_t ws_size,
                              hipStream_t stream) {
    const float* x     = (const float*)d_in[0];
    const int*   ei    = (const int*)d_in[1];
    const int*   batch = (const int*)d_in[2];
    const float* W1    = (const float*)d_in[3];
    const float* asrc1 = (const float*)d_in[4];
    const float* adst1 = (const float*)d_in[5];
    const float* b1    = (const float*)d_in[6];
    const float* W2    = (const float*)d_in[7];
    const float* asrc2 = (const float*)d_in[8];
    const float* adst2 = (const float*)d_in[9];
    const float* b2    = (const float*)d_in[10];
    const float* Wout  = (const float*)d_in[11];
    const float* bout  = (const float*)d_in[12];

    char* ws = (char*)d_ws;
    size_t off = 0;
    auto alloc = [&](size_t bytes) -> void* {
        void* p = ws + off;
        off += (bytes + 255) / 256 * 256;
        return p;
    };
    unsigned char* u_h = (unsigned char*)alloc((size_t)N_NODES * F1);  // fp8 h1
    unsigned char* u_h2 = (unsigned char*)alloc((size_t)N_NODES * F2); // fp8 h2 (layer 2)
    ushortT* u_x2  = (ushortT*)alloc(sizeof(ushortT) * (size_t)N_NODES * F2);
    uint4*   wpk   = (uint4*)alloc(sizeof(uint4) * 8192);  // W1|W2 fragment images
    float*   f_s   = (float*)alloc(sizeof(float) * (size_t)N_NODES * HEADS);
    float*   f_d   = (float*)alloc(sizeof(float) * (size_t)N_NODES * HEADS);
    float*   f_s2  = (float*)alloc(sizeof(float) * (size_t)N_NODES * HEADS);
    float*   f_d2  = (float*)alloc(sizeof(float) * (size_t)N_NODES * HEADS);
    int*     i_cnt = (int*)alloc(sizeof(int) * (size_t)N_NODES);
    int*     i_off = (int*)alloc(sizeof(int) * (size_t)(N_NODES + 1));
    int*     i_rnk = (int*)alloc(sizeof(int) * (size_t)N_EDGES);
    int*     i_csr = (int*)alloc(sizeof(int) * (size_t)N_EDGES);
    int*     i_bnd = (int*)alloc(sizeof(int) * (size_t)(N_GRAPHS + 1));
    int*     i_bs  = (int*)alloc(sizeof(int) * SCAN_NB);
    int*     i_bb  = (int*)alloc(sizeof(int) * SCAN_NB);
    float*   f_prt = (float*)alloc(sizeof(float) * (size_t)N_GRAPHS * 2 * POOL_SPLITS * F2);
    (void)ws_size; (void)in_sizes; (void)n_in; (void)out_size;

    // tiny W-only pack + fused i_cnt zeroing
    k_packw<<<32, 256, 0, stream>>>(W1, W2, wpk, i_cnt);

    // mega: gemm1 (782 blocks, 1 tile/wave) + CSR count-with-rank behind
    k_mega1<<<GEMM_GRID + COUNT_GRID, 256, 0, stream>>>(
        x, wpk, asrc1, adst1, u_h, f_s, f_d, ei, i_cnt, i_rnk);

    // 2-phase scan (+bounds); atomic-free 4-edge/thread scatter
    k_scan1<<<SCAN_NB, SCAN_B, 0, stream>>>(i_cnt, i_off, i_bs);
    k_scan2<<<1, SCAN_B, 0, stream>>>(i_bs, i_bb, i_off, batch, i_bnd);
    k_scatter<<<SCATTER_GRID, 256, 0, stream>>>(ei, i_off, i_bb, i_rnk, i_csr);

    // FUSED agg(L1)+gemm2: 3125 blocks of 16 nodes; u_x1 round-trip deleted
    k_aggemm<<<AGEMM_GRID, 256, 0, stream>>>(
        u_h, f_s, f_d, i_off, i_bb, i_csr, b1, wpk + 4096, asrc2, adst2,
        u_h2, f_s2, f_d2);

    // Layer 2 aggregation (reads h2/s2/d2 — no in-place race with layer 1)
    int agg_grid = N_NODES / (4 * 4);  // 4 nodes/wave, 4 waves/block = 3125
    k_agg<OUT_CH, 8, 4, 64><<<agg_grid, 256, 0, stream>>>(
        u_h2, f_s2, f_d2, i_off, i_bb, i_csr, b2, u_x2);

    // Pool (1024 blocks, uint loads, 32 partials/graph) + tiny head
    dim3 pgrid(N_GRAPHS, POOL_SPLITS);
    k_pool_partial<<<pgrid, F2, 0, stream>>>(u_x2, i_bnd, f_prt);
    k_head<<<N_GRAPHS, F2, 0, stream>>>(f_prt, i_bnd, Wout, bout, (float*)d_out);
}